// Round 11
// baseline (5050.031 us; speedup 1.0000x reference)
//
#include <hip/hip_runtime.h>

#define NODES 40000
#define EDGES 640000

typedef float f32x2v __attribute__((ext_vector_type(2)));

__device__ __forceinline__ float silu_f(float x) { return x / (1.0f + __expf(-x)); }
__device__ __forceinline__ f32x2v mk2(float a, float b) { f32x2v r; r[0] = a; r[1] = b; return r; }

// ---------------------------------------------------------------------------
// Real-basis Clebsch-Gordan contraction, 2 edges packed per call (f32x2v).
// Per-edge op sequence identical to the validated scalar version.
// v: [y,z,x] ; t: [xy,yz,z2,xz,x2y2]
// ---------------------------------------------------------------------------
__device__ __forceinline__ void tp_uuu2(const f32x2v* wv,
                                        f32x2v as, const f32x2v* av, const f32x2v* at,
                                        f32x2v bs, const f32x2v* bv, const f32x2v* bt,
                                        f32x2v& ms, f32x2v* mv, f32x2v* mt)
{
    const float CR = 0.70710678f;
    const float K1 = 0.31622777f;
    const float K3 = 0.54772256f;
    const float KA = 0.40824829f;
    const float KB = 0.70710678f;
    const float KC = 0.81649658f;
    const float L4 = 0.63245553f;
    const float G2 = 0.53452248f;
    const float G1 = 0.26726124f;
    const float HH = 0.46291005f;

    f32x2v os = {0.f, 0.f};
    f32x2v ov0 = {0.f, 0.f}, ov1 = {0.f, 0.f}, ov2 = {0.f, 0.f};
    f32x2v ot0 = {0.f, 0.f}, ot1 = {0.f, 0.f}, ot2 = {0.f, 0.f};
    f32x2v ot3 = {0.f, 0.f}, ot4 = {0.f, 0.f};

    os += wv[0] * as * bs;
    ov0 += wv[1] * as * bv[0]; ov1 += wv[1] * as * bv[1]; ov2 += wv[1] * as * bv[2];
    ot0 += wv[2] * as * bt[0]; ot1 += wv[2] * as * bt[1]; ot2 += wv[2] * as * bt[2];
    ot3 += wv[2] * as * bt[3]; ot4 += wv[2] * as * bt[4];
    ov0 += wv[3] * av[0] * bs; ov1 += wv[3] * av[1] * bs; ov2 += wv[3] * av[2] * bs;
    os += wv[4] * (-0.57735027f) * (av[0]*bv[0] + av[1]*bv[1] + av[2]*bv[2]);
    ov0 += wv[5] * CR * (av[1]*bv[2] - av[2]*bv[1]);
    ov1 += wv[5] * CR * (av[2]*bv[0] - av[0]*bv[2]);
    ov2 += wv[5] * CR * (av[0]*bv[1] - av[1]*bv[0]);
    ot0 += wv[6] * CR * (av[2]*bv[0] + av[0]*bv[2]);
    ot1 += wv[6] * CR * (av[0]*bv[1] + av[1]*bv[0]);
    ot2 += wv[6] * 0.40824829f * (2.f*av[1]*bv[1] - av[2]*bv[2] - av[0]*bv[0]);
    ot3 += wv[6] * CR * (av[2]*bv[1] + av[1]*bv[2]);
    ot4 += wv[6] * CR * (av[2]*bv[2] - av[0]*bv[0]);
    ov0 += wv[7] * (-K3*av[1]*bt[1] + K1*av[0]*bt[2] - K3*av[2]*bt[0] + K3*av[0]*bt[4]);
    ov1 += wv[7] * (-2.f*K1*av[1]*bt[2] - K3*av[2]*bt[3] - K3*av[0]*bt[1]);
    ov2 += wv[7] * (-K3*av[1]*bt[3] + K1*av[2]*bt[2] - K3*av[0]*bt[0] - K3*av[2]*bt[4]);
    ot0 += wv[8] * ( KC*av[1]*bt[4] - KA*av[2]*bt[3] + KA*av[0]*bt[1]);
    ot1 += wv[8] * ( KA*av[1]*bt[3] - KB*av[2]*bt[2] - KA*av[0]*bt[0] - KA*av[2]*bt[4]);
    ot2 += wv[8] * ( KB*av[2]*bt[1] - KB*av[0]*bt[3]);
    ot3 += wv[8] * (-KA*av[1]*bt[1] + KB*av[0]*bt[2] + KA*av[2]*bt[0] - KA*av[0]*bt[4]);
    ot4 += wv[8] * (-KC*av[1]*bt[0] + KA*av[2]*bt[1] + KA*av[0]*bt[3]);
    ot0 += wv[9] * at[0] * bs; ot1 += wv[9] * at[1] * bs; ot2 += wv[9] * at[2] * bs;
    ot3 += wv[9] * at[3] * bs; ot4 += wv[9] * at[4] * bs;
    ov0 += wv[10] * (-K3*bv[1]*at[1] + K1*bv[0]*at[2] - K3*bv[2]*at[0] + K3*bv[0]*at[4]);
    ov1 += wv[10] * (-2.f*K1*bv[1]*at[2] - K3*bv[2]*at[3] - K3*bv[0]*at[1]);
    ov2 += wv[10] * (-K3*bv[1]*at[3] + K1*bv[2]*at[2] - K3*bv[0]*at[0] - K3*bv[2]*at[4]);
    ot0 -= wv[11] * ( KC*bv[1]*at[4] - KA*bv[2]*at[3] + KA*bv[0]*at[1]);
    ot1 -= wv[11] * ( KA*bv[1]*at[3] - KB*bv[2]*at[2] - KA*bv[0]*at[0] - KA*bv[2]*at[4]);
    ot2 -= wv[11] * ( KB*bv[2]*at[1] - KB*bv[0]*at[3]);
    ot3 -= wv[11] * (-KA*bv[1]*at[1] + KB*bv[0]*at[2] + KA*bv[2]*at[0] - KA*bv[0]*at[4]);
    ot4 -= wv[11] * (-KC*bv[1]*at[0] + KA*bv[2]*at[1] + KA*bv[0]*at[3]);
    os += wv[12] * 0.44721360f * (at[0]*bt[0] + at[1]*bt[1] + at[2]*bt[2] + at[3]*bt[3] + at[4]*bt[4]);
    ov0 += wv[13] * ( K1*(at[0]*bt[1] - at[1]*bt[0]) + K3*(at[3]*bt[2] - at[2]*bt[3]) + K1*(at[4]*bt[3] - at[3]*bt[4]) );
    ov1 += wv[13] * ( L4*(at[0]*bt[4] - at[4]*bt[0]) + K1*(at[1]*bt[3] - at[3]*bt[1]) );
    ov2 += wv[13] * ( K1*(at[3]*bt[0] - at[0]*bt[3]) + K3*(at[2]*bt[1] - at[1]*bt[2]) + K1*(at[4]*bt[1] - at[1]*bt[4]) );
    ot0 += wv[14] * ( G2*(at[2]*bt[0] + at[0]*bt[2]) - HH*(at[1]*bt[3] + at[3]*bt[1]) );
    ot1 += wv[14] * (-HH*(at[3]*bt[0] + at[0]*bt[3]) + HH*(at[1]*bt[4] + at[4]*bt[1]) - G1*(at[2]*bt[1] + at[1]*bt[2]) );
    ot2 += wv[14] * ( G2*(at[0]*bt[0] + at[4]*bt[4] - at[2]*bt[2]) - G1*(at[1]*bt[1] + at[3]*bt[3]) );
    ot3 += wv[14] * (-HH*(at[1]*bt[0] + at[0]*bt[1]) - HH*(at[3]*bt[4] + at[4]*bt[3]) - G1*(at[2]*bt[3] + at[3]*bt[2]) );
    ot4 += wv[14] * ( G2*(at[2]*bt[4] + at[4]*bt[2]) + HH*(at[1]*bt[1] - at[3]*bt[3]) );

    ms = os * 0.57735027f;
    mv[0] = ov0 * 0.40824829f; mv[1] = ov1 * 0.40824829f; mv[2] = ov2 * 0.40824829f;
    mt[0] = ot0 * 0.40824829f; mt[1] = ot1 * 0.40824829f; mt[2] = ot2 * 0.40824829f;
    mt[3] = ot3 * 0.40824829f; mt[4] = ot4 * 0.40824829f;
}

// ---------------------------------------------------------------------------
// CSR construction + fused permutation (slot order = dst-sorted)
// ---------------------------------------------------------------------------
__global__ void deg_kernel(const int* __restrict__ eidx, int* __restrict__ deg)
{
    int e = blockIdx.x * 256 + threadIdx.x;
    if (e < EDGES) atomicAdd(&deg[eidx[EDGES + e]], 1);
}

__launch_bounds__(1024)
__global__ void scan_kernel(const int* __restrict__ deg, int* __restrict__ off,
                            int* __restrict__ cursor)
{
    __shared__ int part[1024];
    const int t = threadIdx.x;
    const int base = t * 40;     // threads 0..999 cover exactly 40000
    int v[40];
    if (t < 1000) {
        const int4* p4 = (const int4*)(deg + base);
        #pragma unroll
        for (int i = 0; i < 10; ++i) {
            int4 q = p4[i];
            v[4 * i + 0] = q.x; v[4 * i + 1] = q.y;
            v[4 * i + 2] = q.z; v[4 * i + 3] = q.w;
        }
    } else {
        #pragma unroll
        for (int i = 0; i < 40; ++i) v[i] = 0;
    }
    int loc[40];
    int s = 0;
    #pragma unroll
    for (int i = 0; i < 40; ++i) { loc[i] = s; s += v[i]; }
    part[t] = s;
    __syncthreads();
    for (int d = 1; d < 1024; d <<= 1) {
        int vv = (t >= d) ? part[t - d] : 0;
        __syncthreads();
        part[t] += vv;
        __syncthreads();
    }
    int tb = (t == 0) ? 0 : part[t - 1];
    if (t < 1000) {
        #pragma unroll
        for (int i = 0; i < 40; ++i) {
            off[base + i] = tb + loc[i];
            cursor[base + i] = tb + loc[i];
        }
    }
    if (t == 1023) off[NODES] = part[1023];
}

// build + permute fused: scatter srcs/evp into CSR slot order directly
__global__ void build_kernel(const int* __restrict__ eidx, const float* __restrict__ ev,
                             int* __restrict__ cursor,
                             float* __restrict__ evp, int* __restrict__ srcs)
{
    int e = blockIdx.x * 256 + threadIdx.x;
    if (e < EDGES) {
        int dst = eidx[EDGES + e];
        int p = atomicAdd(&cursor[dst], 1);
        srcs[p] = eidx[e];
        evp[p * 3 + 0] = ev[e * 3 + 0];
        evp[p * 3 + 1] = ev[e * 3 + 1];
        evp[p * 3 + 2] = ev[e * 3 + 2];
    }
}

// ---------------------------------------------------------------------------
// Layer 0: 128-edge blocks, 4 edges/lane (r10-proven, bit-identical to r8).
// ---------------------------------------------------------------------------
__launch_bounds__(256, 3)
__global__ void layer0_edge(const float* __restrict__ evp, const int* __restrict__ srcs,
                            const int* __restrict__ xs, const float* __restrict__ embw,
                            const float* __restrict__ w1, const float* __restrict__ b1,
                            const float* __restrict__ w2, const float* __restrict__ b2,
                            float* __restrict__ mbuf)
{
    __shared__ float emb_s[128 * 17];
    __shared__ float hid_s[128 * 68];
    __shared__ float w2t[24 * 68];
    const int tid = threadIdx.x;
    const int e0 = blockIdx.x * 128;

    for (int idx = tid; idx < 64 * 24; idx += 256) {
        int j = idx / 24, o = idx - j * 24;
        w2t[o * 68 + j] = w2[idx];
    }
    for (int idx = tid; idx < 2048; idx += 256) {
        int e = idx >> 4, i = idx & 15;
        const float* ep = evp + (size_t)(e0 + e) * 3;
        float ex = ep[0], ey = ep[1], ez = ep[2];
        float r = sqrtf(ex * ex + ey * ey + ez * ez + 1e-12f);
        float d = r * (17.0f / 3.0f) - (float)(i + 1);
        float f = 0.0f;
        if (fabsf(d) < 1.0f) f = 8.433572869f * __expf(-2.0f / (1.0f - d * d));
        emb_s[e * 17 + i] = f;
    }
    __syncthreads();

    {
        const int egp = tid >> 3;
        const int jb = (tid & 7) * 8;
        float acc2[4][8];
        #pragma unroll
        for (int el = 0; el < 4; ++el)
            #pragma unroll
            for (int k = 0; k < 8; ++k) acc2[el][k] = b1[jb + k];
        #pragma unroll
        for (int i = 0; i < 16; ++i) {
            float4 wa = *(const float4*)&w1[i * 64 + jb];
            float4 wb = *(const float4*)&w1[i * 64 + jb + 4];
            #pragma unroll
            for (int el = 0; el < 4; ++el) {
                float evv = emb_s[(egp * 4 + el) * 17 + i];
                acc2[el][0] += evv * wa.x; acc2[el][1] += evv * wa.y;
                acc2[el][2] += evv * wa.z; acc2[el][3] += evv * wa.w;
                acc2[el][4] += evv * wb.x; acc2[el][5] += evv * wb.y;
                acc2[el][6] += evv * wb.z; acc2[el][7] += evv * wb.w;
            }
        }
        #pragma unroll
        for (int el = 0; el < 4; ++el)
            #pragma unroll
            for (int k = 0; k < 8; ++k)
                hid_s[(egp * 4 + el) * 68 + jb + k] = silu_f(acc2[el][k]);
    }
    __syncthreads();

    const int c = tid & 7, g = (tid >> 3) & 7, wv_ = tid >> 6;
    float wacc[3][4];
    #pragma unroll
    for (int p = 0; p < 3; ++p) {
        float bb = b2[p * 8 + c];
        #pragma unroll
        for (int q = 0; q < 4; ++q) wacc[p][q] = bb;
    }
    for (int jb = 0; jb < 64; jb += 4) {
        float4 h4[4];
        #pragma unroll
        for (int q = 0; q < 4; ++q)
            h4[q] = *(const float4*)&hid_s[(wv_ * 32 + q * 8 + g) * 68 + jb];
        #pragma unroll
        for (int p = 0; p < 3; ++p) {
            float4 w4 = *(const float4*)&w2t[(p * 8 + c) * 68 + jb];
            #pragma unroll
            for (int q = 0; q < 4; ++q)
                wacc[p][q] += h4[q].x * w4.x + h4[q].y * w4.y + h4[q].z * w4.z + h4[q].w * w4.w;
        }
    }

    const int ebase = wv_ * 32 + g;
    const float c3 = 1.7320508f, c15 = 3.8729833f, c5 = 2.2360680f;
    #pragma unroll
    for (int q = 0; q < 4; ++q) {
        const int sl = e0 + ebase + 8 * q;
        const int sn = srcs[sl];
        float hs = embw[xs[sn] * 8 + c];
        const float* ep = evp + (size_t)sl * 3;
        float ex = ep[0], ey = ep[1], ez = ep[2];
        float r = sqrtf(ex * ex + ey * ey + ez * ez + 1e-12f);
        float inv = 1.0f / r;
        float x = ex * inv, y = ey * inv, z = ez * inv;

        float* me = mbuf + (size_t)sl * 72 + c * 9;
        me[0] = wacc[0][q] * hs;
        me[1] = wacc[1][q] * hs * (c3 * y);
        me[2] = wacc[1][q] * hs * (c3 * z);
        me[3] = wacc[1][q] * hs * (c3 * x);
        me[4] = wacc[2][q] * hs * (c15 * x * y);
        me[5] = wacc[2][q] * hs * (c15 * y * z);
        me[6] = wacc[2][q] * hs * (0.5f * c5 * (3.f * z * z - 1.f));
        me[7] = wacc[2][q] * hs * (c15 * x * z);
        me[8] = wacc[2][q] * hs * (0.5f * c15 * (x * x - y * y));
    }
}

// ---------------------------------------------------------------------------
// Layers 1/2: pk-fp32 tp_edge with w2t staged in TWO K-column passes
// (jb 0..31, then 32..63). acc visits jb in the same ascending order as the
// single-pass version -> bit-identical results. LDS: w2t fp32 [120][36]
// (17,280 B, emb aliased) + hid bf16 [128][72] (18,432 B) = 35,712 B
// -> 4 blocks/CU, 16 waves (was 3 blocks/12 waves at 51 KB).
// ---------------------------------------------------------------------------
__launch_bounds__(256, 4)
__global__ void tp_edge(const float* __restrict__ evp, const int* __restrict__ srcs,
                        const float* __restrict__ h,
                        const float* __restrict__ w1, const float* __restrict__ b1,
                        const float* __restrict__ w2, const float* __restrict__ b2,
                        float* __restrict__ mbuf)
{
    __shared__ float w2t[120 * 36];            // 17,280 B; emb_s aliased (needs 8,704)
    __shared__ unsigned short hid_s[128 * 72]; // 18,432 B
    float* emb_s = w2t;

    const int tid = threadIdx.x;
    const int e0 = blockIdx.x * 128;

    // Phase A: soft one-hot -> emb_s[e*17+i]
    for (int idx = tid; idx < 2048; idx += 256) {
        int e = idx >> 4, i = idx & 15;
        const float* ep = evp + (size_t)(e0 + e) * 3;
        float ex = ep[0], ey = ep[1], ez = ep[2];
        float r = sqrtf(ex * ex + ey * ey + ez * ez + 1e-12f);
        float d = r * (17.0f / 3.0f) - (float)(i + 1);
        float f = 0.0f;
        if (fabsf(d) < 1.0f) f = 8.433572869f * __expf(-2.0f / (1.0f - d * d));
        emb_s[e * 17 + i] = f;
    }
    __syncthreads();

    // Phase B: hidden = silu(emb @ w1 + b1), 4 edges/thread packed as 2 pairs
    {
        const int egp = tid >> 3;
        const int jb = (tid & 7) * 8;
        f32x2v acc2[2][8];
        #pragma unroll
        for (int pr = 0; pr < 2; ++pr)
            #pragma unroll
            for (int k = 0; k < 8; ++k) { float bb = b1[jb + k]; acc2[pr][k] = mk2(bb, bb); }
        #pragma unroll
        for (int i = 0; i < 16; ++i) {
            float4 wa = *(const float4*)&w1[i * 64 + jb];
            float4 wb = *(const float4*)&w1[i * 64 + jb + 4];
            #pragma unroll
            for (int pr = 0; pr < 2; ++pr) {
                f32x2v evv = mk2(emb_s[(egp * 4 + 2 * pr) * 17 + i],
                                 emb_s[(egp * 4 + 2 * pr + 1) * 17 + i]);
                acc2[pr][0] += evv * wa.x; acc2[pr][1] += evv * wa.y;
                acc2[pr][2] += evv * wa.z; acc2[pr][3] += evv * wa.w;
                acc2[pr][4] += evv * wb.x; acc2[pr][5] += evv * wb.y;
                acc2[pr][6] += evv * wb.z; acc2[pr][7] += evv * wb.w;
            }
        }
        #pragma unroll
        for (int pr = 0; pr < 2; ++pr) {
            #pragma unroll
            for (int u = 0; u < 2; ++u) {
                unsigned int us[8];
                #pragma unroll
                for (int k = 0; k < 8; ++k) {
                    unsigned int b = __float_as_uint(silu_f(acc2[pr][k][u]));
                    b += 0x7fffu + ((b >> 16) & 1u);
                    us[k] = b >> 16;
                }
                uint4 pk;
                pk.x = us[0] | (us[1] << 16);
                pk.y = us[2] | (us[3] << 16);
                pk.z = us[4] | (us[5] << 16);
                pk.w = us[6] | (us[7] << 16);
                *(uint4*)&hid_s[(egp * 4 + 2 * pr + u) * 72 + jb] = pk;
            }
        }
    }

    // Phase C/D: two K-column passes; acc order = jb ascending (bit-identical)
    const int c = tid & 7, g = (tid >> 3) & 7, wv_ = tid >> 6;
    f32x2v acc[15][2];
    #pragma unroll
    for (int p = 0; p < 15; ++p) {
        float bb = b2[p * 8 + c];
        acc[p][0] = mk2(bb, bb);
        acc[p][1] = mk2(bb, bb);
    }

    #pragma unroll
    for (int half = 0; half < 2; ++half) {
        const int col0 = half * 32;
        __syncthreads();   // half0: emb reads done; half1: D-half0 w2t reads done
        for (int idx = tid; idx < 32 * 120; idx += 256) {
            int j = idx / 120, o = idx - j * 120;      // j in 0..31
            w2t[o * 36 + j] = w2[(col0 + j) * 120 + o];
        }
        __syncthreads();

        for (int jb = 0; jb < 32; jb += 8) {
            f32x2v hf[8][2];
            #pragma unroll
            for (int pr = 0; pr < 2; ++pr) {
                uint4 h0 = *(const uint4*)&hid_s[(wv_ * 32 + (2 * pr) * 8 + g) * 72 + col0 + jb];
                uint4 h1 = *(const uint4*)&hid_s[(wv_ * 32 + (2 * pr + 1) * 8 + g) * 72 + col0 + jb];
                hf[0][pr] = mk2(__uint_as_float(h0.x << 16),        __uint_as_float(h1.x << 16));
                hf[1][pr] = mk2(__uint_as_float(h0.x & 0xffff0000u), __uint_as_float(h1.x & 0xffff0000u));
                hf[2][pr] = mk2(__uint_as_float(h0.y << 16),        __uint_as_float(h1.y << 16));
                hf[3][pr] = mk2(__uint_as_float(h0.y & 0xffff0000u), __uint_as_float(h1.y & 0xffff0000u));
                hf[4][pr] = mk2(__uint_as_float(h0.z << 16),        __uint_as_float(h1.z << 16));
                hf[5][pr] = mk2(__uint_as_float(h0.z & 0xffff0000u), __uint_as_float(h1.z & 0xffff0000u));
                hf[6][pr] = mk2(__uint_as_float(h0.w << 16),        __uint_as_float(h1.w << 16));
                hf[7][pr] = mk2(__uint_as_float(h0.w & 0xffff0000u), __uint_as_float(h1.w & 0xffff0000u));
            }
            #pragma unroll
            for (int p = 0; p < 15; ++p) {
                float4 wa = *(const float4*)&w2t[(p * 8 + c) * 36 + jb];
                float4 wb = *(const float4*)&w2t[(p * 8 + c) * 36 + jb + 4];
                #pragma unroll
                for (int pr = 0; pr < 2; ++pr) {
                    acc[p][pr] += hf[0][pr] * wa.x + hf[1][pr] * wa.y + hf[2][pr] * wa.z + hf[3][pr] * wa.w
                                + hf[4][pr] * wb.x + hf[5][pr] * wb.y + hf[6][pr] * wb.z + hf[7][pr] * wb.w;
                }
            }
        }
    }

    // Tail: 2 pairs of edges, packed tp_uuu; gathers hoisted per pair
    const int ebase = wv_ * 32 + g;
    int sn[4];
    #pragma unroll
    for (int q = 0; q < 4; ++q) sn[q] = srcs[e0 + ebase + 8 * q];

    #pragma unroll
    for (int hh = 0; hh < 2; ++hh) {
        const float* hn0 = h + (size_t)sn[2 * hh] * 72 + c * 9;
        const float* hn1 = h + (size_t)sn[2 * hh + 1] * 72 + c * 9;
        const float* me0 = mbuf + (size_t)(e0 + ebase + 8 * (2 * hh)) * 72 + c * 9;
        const float* me1 = mbuf + (size_t)(e0 + ebase + 8 * (2 * hh + 1)) * 72 + c * 9;

        f32x2v as = mk2(hn0[0], hn1[0]);
        f32x2v av[3], at[5], bv[3], bt[5];
        #pragma unroll
        for (int i = 0; i < 3; ++i) av[i] = mk2(hn0[1 + i], hn1[1 + i]);
        #pragma unroll
        for (int i = 0; i < 5; ++i) at[i] = mk2(hn0[4 + i], hn1[4 + i]);
        f32x2v bs = mk2(silu_f(me0[0]), silu_f(me1[0]));
        #pragma unroll
        for (int i = 0; i < 3; ++i) bv[i] = mk2(me0[1 + i], me1[1 + i]);
        #pragma unroll
        for (int i = 0; i < 5; ++i) bt[i] = mk2(me0[4 + i], me1[4 + i]);

        f32x2v wvv[15];
        #pragma unroll
        for (int p = 0; p < 15; ++p) wvv[p] = acc[p][hh];

        f32x2v ms, mv[3], mt[5];
        tp_uuu2(wvv, as, av, at, bs, bv, bt, ms, mv, mt);

        float* mo0 = mbuf + (size_t)(e0 + ebase + 8 * (2 * hh)) * 72 + c * 9;
        float* mo1 = mbuf + (size_t)(e0 + ebase + 8 * (2 * hh + 1)) * 72 + c * 9;
        mo0[0] = ms[0]; mo1[0] = ms[1];
        #pragma unroll
        for (int i = 0; i < 3; ++i) { mo0[1 + i] = mv[i][0]; mo1[1 + i] = mv[i][1]; }
        #pragma unroll
        for (int i = 0; i < 5; ++i) { mo0[4 + i] = mt[i][0]; mo1[4 + i] = mt[i][1]; }
    }
}

// ---------------------------------------------------------------------------
// Node updates: sequential CSR-span gather of slot-ordered mbuf
// ---------------------------------------------------------------------------
__global__ void node0(const int* __restrict__ xs, const float* __restrict__ embw,
                      const float* __restrict__ lin0, const float* __restrict__ mbuf,
                      const int* __restrict__ off, float* __restrict__ h)
{
    int idx = blockIdx.x * 256 + threadIdx.x;
    int n = idx >> 3, c = idx & 7;
    int xb = xs[n] * 8;
    float dot = 0.f;
    #pragma unroll
    for (int d = 0; d < 8; ++d) dot += embw[xb + d] * lin0[d * 8 + c];

    float an[9];
    #pragma unroll
    for (int i = 0; i < 9; ++i) an[i] = 0.f;
    const int beg = off[n], end = off[n + 1];
    for (int p = beg; p < end; ++p) {
        const float* me = mbuf + (size_t)p * 72 + c * 9;
        #pragma unroll
        for (int i = 0; i < 9; ++i) an[i] += me[i];
    }

    float* hn = h + (size_t)n * 72 + c * 9;
    hn[0] = silu_f(an[0] * 0.25f + dot * 0.35355339f);
    #pragma unroll
    for (int i = 1; i < 9; ++i) hn[i] = an[i] * 0.25f;
}

__global__ void node12(const float* __restrict__ hin, const float* __restrict__ lin,
                       const float* __restrict__ mbuf, const int* __restrict__ off,
                       float* __restrict__ hout)
{
    int idx = blockIdx.x * 256 + threadIdx.x;
    int n = idx >> 3, d = idx & 7;

    float an[9];
    #pragma unroll
    for (int i = 0; i < 9; ++i) an[i] = 0.f;
    const int beg = off[n], end = off[n + 1];
    for (int p = beg; p < end; ++p) {
        const float* me = mbuf + (size_t)p * 72 + d * 9;
        #pragma unroll
        for (int i = 0; i < 9; ++i) an[i] += me[i];
    }

    const float* hn = hin + (size_t)n * 72;
    float* ho = hout + (size_t)n * 72 + d * 9;

    float s = 0.f;
    #pragma unroll
    for (int c = 0; c < 8; ++c) s += hn[c * 9] * lin[c * 8 + d];
    ho[0] = silu_f(s * 0.35355339f + an[0] * 0.25f);
    #pragma unroll
    for (int i = 0; i < 3; ++i) {
        float v = 0.f;
        #pragma unroll
        for (int c = 0; c < 8; ++c) v += hn[c * 9 + 1 + i] * lin[64 + c * 8 + d];
        ho[1 + i] = v * 0.35355339f + an[1 + i] * 0.25f;
    }
    #pragma unroll
    for (int i = 0; i < 5; ++i) {
        float t = 0.f;
        #pragma unroll
        for (int c = 0; c < 8; ++c) t += hn[c * 9 + 4 + i] * lin[128 + c * 8 + d];
        ho[4 + i] = t * 0.35355339f + an[4 + i] * 0.25f;
    }
}

// Fused final node update + output head: h record staged in LDS, never HBM
__global__ void node12_out(const float* __restrict__ hin, const float* __restrict__ lin,
                           const float* __restrict__ mbuf, const int* __restrict__ off,
                           const float* __restrict__ outw, float* __restrict__ out)
{
    __shared__ float hrec[32][72];
    int idx = blockIdx.x * 256 + threadIdx.x;
    int n = idx >> 3, d = idx & 7;
    int nl = threadIdx.x >> 3;

    float an[9];
    #pragma unroll
    for (int i = 0; i < 9; ++i) an[i] = 0.f;
    const int beg = off[n], end = off[n + 1];
    for (int p = beg; p < end; ++p) {
        const float* me = mbuf + (size_t)p * 72 + d * 9;
        #pragma unroll
        for (int i = 0; i < 9; ++i) an[i] += me[i];
    }

    const float* hn = hin + (size_t)n * 72;
    float* ho = &hrec[nl][d * 9];

    float s = 0.f;
    #pragma unroll
    for (int c = 0; c < 8; ++c) s += hn[c * 9] * lin[c * 8 + d];
    ho[0] = silu_f(s * 0.35355339f + an[0] * 0.25f);
    #pragma unroll
    for (int i = 0; i < 3; ++i) {
        float v = 0.f;
        #pragma unroll
        for (int c = 0; c < 8; ++c) v += hn[c * 9 + 1 + i] * lin[64 + c * 8 + d];
        ho[1 + i] = v * 0.35355339f + an[1 + i] * 0.25f;
    }
    #pragma unroll
    for (int i = 0; i < 5; ++i) {
        float t = 0.f;
        #pragma unroll
        for (int c = 0; c < 8; ++c) t += hn[c * 9 + 4 + i] * lin[128 + c * 8 + d];
        ho[4 + i] = t * 0.35355339f + an[4 + i] * 0.25f;
    }
    __syncthreads();

    const float* hr = &hrec[nl][0];
    float sv[8], vv[24], tv[40];
    #pragma unroll
    for (int i = 0; i < 8; ++i) {
        sv[i] = hr[i * 9];
        #pragma unroll
        for (int q = 0; q < 3; ++q) vv[i * 3 + q] = hr[i * 9 + 1 + q];
        #pragma unroll
        for (int q = 0; q < 5; ++q) tv[i * 5 + q] = hr[i * 9 + 4 + q];
    }
    float acc = 0.f;
    #pragma unroll
    for (int i = 0; i < 8; ++i) {
        #pragma unroll
        for (int j = 0; j < 8; ++j) {
            float dv = vv[i*3+0]*vv[j*3+0] + vv[i*3+1]*vv[j*3+1] + vv[i*3+2]*vv[j*3+2];
            float dt = tv[i*5+0]*tv[j*5+0] + tv[i*5+1]*tv[j*5+1] + tv[i*5+2]*tv[j*5+2]
                     + tv[i*5+3]*tv[j*5+3] + tv[i*5+4]*tv[j*5+4];
            int o = (i * 8 + j) * 8 + d;
            acc += sv[i] * sv[j] * outw[o]
                 + dv * 0.57735027f * outw[512 + o]
                 + dt * 0.44721360f * outw[1024 + o];
        }
    }
    out[n * 8 + d] = acc * 0.072168784f;
}

// ---------------------------------------------------------------------------
extern "C" void kernel_launch(void* const* d_in, const int* in_sizes, int n_in,
                              void* d_out, int out_size, void* d_ws, size_t ws_size,
                              hipStream_t stream)
{
    const int*   x    = (const int*)  d_in[0];
    const int*   eidx = (const int*)  d_in[1];
    const float* ev   = (const float*)d_in[2];
    const float* embw = (const float*)d_in[3];
    const float* lin0 = (const float*)d_in[4];
    const float* lin1 = (const float*)d_in[5];
    const float* lin2 = (const float*)d_in[6];
    const float* outw = (const float*)d_in[7];
    const float* r0w1 = (const float*)d_in[8];
    const float* r0b1 = (const float*)d_in[9];
    const float* r0w2 = (const float*)d_in[10];
    const float* r0b2 = (const float*)d_in[11];
    const float* r1w1 = (const float*)d_in[12];
    const float* r1b1 = (const float*)d_in[13];
    const float* r1w2 = (const float*)d_in[14];
    const float* r1b2 = (const float*)d_in[15];
    const float* r2w1 = (const float*)d_in[16];
    const float* r2b1 = (const float*)d_in[17];
    const float* r2w2 = (const float*)d_in[18];
    const float* r2b2 = (const float*)d_in[19];

    float* mbuf = (float*)d_ws;                          // EDGES*72 f32
    float* hA   = mbuf + (size_t)EDGES * 72;             // NODES*72
    float* hB   = hA + (size_t)NODES * 72;               // NODES*72
    float* evp  = hB + (size_t)NODES * 72;               // EDGES*3
    int*   deg    = (int*)(evp + (size_t)EDGES * 3);     // NODES
    int*   off    = deg + NODES;                         // NODES+1
    int*   cursor = off + NODES + 1;                     // NODES
    int*   srcs   = cursor + NODES;                      // EDGES

    const int EBI = (EDGES + 255) / 256;
    const int EB  = EDGES / 128;
    const int NBK = NODES * 8 / 256;

    // CSR build + fused permutation
    hipMemsetAsync(deg, 0, NODES * sizeof(int), stream);
    deg_kernel<<<EBI, 256, 0, stream>>>(eidx, deg);
    scan_kernel<<<1, 1024, 0, stream>>>(deg, off, cursor);
    build_kernel<<<EBI, 256, 0, stream>>>(eidx, ev, cursor, evp, srcs);

    // Layer 0
    layer0_edge<<<EB, 256, 0, stream>>>(evp, srcs, x, embw, r0w1, r0b1, r0w2, r0b2, mbuf);
    node0<<<NBK, 256, 0, stream>>>(x, embw, lin0, mbuf, off, hA);

    // Layer 1
    tp_edge<<<EB, 256, 0, stream>>>(evp, srcs, hA, r1w1, r1b1, r1w2, r1b2, mbuf);
    node12<<<NBK, 256, 0, stream>>>(hA, lin1, mbuf, off, hB);

    // Layer 2 + output head (fused)
    tp_edge<<<EB, 256, 0, stream>>>(evp, srcs, hB, r2w1, r2b1, r2w2, r2b2, mbuf);
    node12_out<<<NBK, 256, 0, stream>>>(hB, lin2, mbuf, off, outw, (float*)d_out);
}

// Round 12
// 4158.153 us; speedup vs baseline: 1.2145x; 1.2145x over previous
//
#include <hip/hip_runtime.h>

#define NODES 40000
#define EDGES 640000

typedef float f32x2v __attribute__((ext_vector_type(2)));

__device__ __forceinline__ float silu_f(float x) { return x / (1.0f + __expf(-x)); }
__device__ __forceinline__ f32x2v mk2(float a, float b) { f32x2v r; r[0] = a; r[1] = b; return r; }

// ---------------------------------------------------------------------------
// Real-basis Clebsch-Gordan contraction, 2 edges packed per call (f32x2v).
// Per-edge op sequence identical to the validated scalar version.
// v: [y,z,x] ; t: [xy,yz,z2,xz,x2y2]
// ---------------------------------------------------------------------------
__device__ __forceinline__ void tp_uuu2(const f32x2v* wv,
                                        f32x2v as, const f32x2v* av, const f32x2v* at,
                                        f32x2v bs, const f32x2v* bv, const f32x2v* bt,
                                        f32x2v& ms, f32x2v* mv, f32x2v* mt)
{
    const float CR = 0.70710678f;
    const float K1 = 0.31622777f;
    const float K3 = 0.54772256f;
    const float KA = 0.40824829f;
    const float KB = 0.70710678f;
    const float KC = 0.81649658f;
    const float L4 = 0.63245553f;
    const float G2 = 0.53452248f;
    const float G1 = 0.26726124f;
    const float HH = 0.46291005f;

    f32x2v os = {0.f, 0.f};
    f32x2v ov0 = {0.f, 0.f}, ov1 = {0.f, 0.f}, ov2 = {0.f, 0.f};
    f32x2v ot0 = {0.f, 0.f}, ot1 = {0.f, 0.f}, ot2 = {0.f, 0.f};
    f32x2v ot3 = {0.f, 0.f}, ot4 = {0.f, 0.f};

    os += wv[0] * as * bs;
    ov0 += wv[1] * as * bv[0]; ov1 += wv[1] * as * bv[1]; ov2 += wv[1] * as * bv[2];
    ot0 += wv[2] * as * bt[0]; ot1 += wv[2] * as * bt[1]; ot2 += wv[2] * as * bt[2];
    ot3 += wv[2] * as * bt[3]; ot4 += wv[2] * as * bt[4];
    ov0 += wv[3] * av[0] * bs; ov1 += wv[3] * av[1] * bs; ov2 += wv[3] * av[2] * bs;
    os += wv[4] * (-0.57735027f) * (av[0]*bv[0] + av[1]*bv[1] + av[2]*bv[2]);
    ov0 += wv[5] * CR * (av[1]*bv[2] - av[2]*bv[1]);
    ov1 += wv[5] * CR * (av[2]*bv[0] - av[0]*bv[2]);
    ov2 += wv[5] * CR * (av[0]*bv[1] - av[1]*bv[0]);
    ot0 += wv[6] * CR * (av[2]*bv[0] + av[0]*bv[2]);
    ot1 += wv[6] * CR * (av[0]*bv[1] + av[1]*bv[0]);
    ot2 += wv[6] * 0.40824829f * (2.f*av[1]*bv[1] - av[2]*bv[2] - av[0]*bv[0]);
    ot3 += wv[6] * CR * (av[2]*bv[1] + av[1]*bv[2]);
    ot4 += wv[6] * CR * (av[2]*bv[2] - av[0]*bv[0]);
    ov0 += wv[7] * (-K3*av[1]*bt[1] + K1*av[0]*bt[2] - K3*av[2]*bt[0] + K3*av[0]*bt[4]);
    ov1 += wv[7] * (-2.f*K1*av[1]*bt[2] - K3*av[2]*bt[3] - K3*av[0]*bt[1]);
    ov2 += wv[7] * (-K3*av[1]*bt[3] + K1*av[2]*bt[2] - K3*av[0]*bt[0] - K3*av[2]*bt[4]);
    ot0 += wv[8] * ( KC*av[1]*bt[4] - KA*av[2]*bt[3] + KA*av[0]*bt[1]);
    ot1 += wv[8] * ( KA*av[1]*bt[3] - KB*av[2]*bt[2] - KA*av[0]*bt[0] - KA*av[2]*bt[4]);
    ot2 += wv[8] * ( KB*av[2]*bt[1] - KB*av[0]*bt[3]);
    ot3 += wv[8] * (-KA*av[1]*bt[1] + KB*av[0]*bt[2] + KA*av[2]*bt[0] - KA*av[0]*bt[4]);
    ot4 += wv[8] * (-KC*av[1]*bt[0] + KA*av[2]*bt[1] + KA*av[0]*bt[3]);
    ot0 += wv[9] * at[0] * bs; ot1 += wv[9] * at[1] * bs; ot2 += wv[9] * at[2] * bs;
    ot3 += wv[9] * at[3] * bs; ot4 += wv[9] * at[4] * bs;
    ov0 += wv[10] * (-K3*bv[1]*at[1] + K1*bv[0]*at[2] - K3*bv[2]*at[0] + K3*bv[0]*at[4]);
    ov1 += wv[10] * (-2.f*K1*bv[1]*at[2] - K3*bv[2]*at[3] - K3*bv[0]*at[1]);
    ov2 += wv[10] * (-K3*bv[1]*at[3] + K1*bv[2]*at[2] - K3*bv[0]*at[0] - K3*bv[2]*at[4]);
    ot0 -= wv[11] * ( KC*bv[1]*at[4] - KA*bv[2]*at[3] + KA*bv[0]*at[1]);
    ot1 -= wv[11] * ( KA*bv[1]*at[3] - KB*bv[2]*at[2] - KA*bv[0]*at[0] - KA*bv[2]*at[4]);
    ot2 -= wv[11] * ( KB*bv[2]*at[1] - KB*bv[0]*at[3]);
    ot3 -= wv[11] * (-KA*bv[1]*at[1] + KB*bv[0]*at[2] + KA*bv[2]*at[0] - KA*bv[0]*at[4]);
    ot4 -= wv[11] * (-KC*bv[1]*at[0] + KA*bv[2]*at[1] + KA*bv[0]*at[3]);
    os += wv[12] * 0.44721360f * (at[0]*bt[0] + at[1]*bt[1] + at[2]*bt[2] + at[3]*bt[3] + at[4]*bt[4]);
    ov0 += wv[13] * ( K1*(at[0]*bt[1] - at[1]*bt[0]) + K3*(at[3]*bt[2] - at[2]*bt[3]) + K1*(at[4]*bt[3] - at[3]*bt[4]) );
    ov1 += wv[13] * ( L4*(at[0]*bt[4] - at[4]*bt[0]) + K1*(at[1]*bt[3] - at[3]*bt[1]) );
    ov2 += wv[13] * ( K1*(at[3]*bt[0] - at[0]*bt[3]) + K3*(at[2]*bt[1] - at[1]*bt[2]) + K1*(at[4]*bt[1] - at[1]*bt[4]) );
    ot0 += wv[14] * ( G2*(at[2]*bt[0] + at[0]*bt[2]) - HH*(at[1]*bt[3] + at[3]*bt[1]) );
    ot1 += wv[14] * (-HH*(at[3]*bt[0] + at[0]*bt[3]) + HH*(at[1]*bt[4] + at[4]*bt[1]) - G1*(at[2]*bt[1] + at[1]*bt[2]) );
    ot2 += wv[14] * ( G2*(at[0]*bt[0] + at[4]*bt[4] - at[2]*bt[2]) - G1*(at[1]*bt[1] + at[3]*bt[3]) );
    ot3 += wv[14] * (-HH*(at[1]*bt[0] + at[0]*bt[1]) - HH*(at[3]*bt[4] + at[4]*bt[3]) - G1*(at[2]*bt[3] + at[3]*bt[2]) );
    ot4 += wv[14] * ( G2*(at[2]*bt[4] + at[4]*bt[2]) + HH*(at[1]*bt[1] - at[3]*bt[3]) );

    ms = os * 0.57735027f;
    mv[0] = ov0 * 0.40824829f; mv[1] = ov1 * 0.40824829f; mv[2] = ov2 * 0.40824829f;
    mt[0] = ot0 * 0.40824829f; mt[1] = ot1 * 0.40824829f; mt[2] = ot2 * 0.40824829f;
    mt[3] = ot3 * 0.40824829f; mt[4] = ot4 * 0.40824829f;
}

// ---------------------------------------------------------------------------
// CSR construction + fused permutation (slot order = dst-sorted)
// ---------------------------------------------------------------------------
__global__ void deg_kernel(const int* __restrict__ eidx, int* __restrict__ deg)
{
    int e = blockIdx.x * 256 + threadIdx.x;
    if (e < EDGES) atomicAdd(&deg[eidx[EDGES + e]], 1);
}

__launch_bounds__(1024)
__global__ void scan_kernel(const int* __restrict__ deg, int* __restrict__ off,
                            int* __restrict__ cursor)
{
    __shared__ int part[1024];
    const int t = threadIdx.x;
    const int base = t * 40;     // threads 0..999 cover exactly 40000
    int v[40];
    if (t < 1000) {
        const int4* p4 = (const int4*)(deg + base);
        #pragma unroll
        for (int i = 0; i < 10; ++i) {
            int4 q = p4[i];
            v[4 * i + 0] = q.x; v[4 * i + 1] = q.y;
            v[4 * i + 2] = q.z; v[4 * i + 3] = q.w;
        }
    } else {
        #pragma unroll
        for (int i = 0; i < 40; ++i) v[i] = 0;
    }
    int loc[40];
    int s = 0;
    #pragma unroll
    for (int i = 0; i < 40; ++i) { loc[i] = s; s += v[i]; }
    part[t] = s;
    __syncthreads();
    for (int d = 1; d < 1024; d <<= 1) {
        int vv = (t >= d) ? part[t - d] : 0;
        __syncthreads();
        part[t] += vv;
        __syncthreads();
    }
    int tb = (t == 0) ? 0 : part[t - 1];
    if (t < 1000) {
        #pragma unroll
        for (int i = 0; i < 40; ++i) {
            off[base + i] = tb + loc[i];
            cursor[base + i] = tb + loc[i];
        }
    }
    if (t == 1023) off[NODES] = part[1023];
}

// build + permute fused: scatter srcs/evp into CSR slot order directly
__global__ void build_kernel(const int* __restrict__ eidx, const float* __restrict__ ev,
                             int* __restrict__ cursor,
                             float* __restrict__ evp, int* __restrict__ srcs)
{
    int e = blockIdx.x * 256 + threadIdx.x;
    if (e < EDGES) {
        int dst = eidx[EDGES + e];
        int p = atomicAdd(&cursor[dst], 1);
        srcs[p] = eidx[e];
        evp[p * 3 + 0] = ev[e * 3 + 0];
        evp[p * 3 + 1] = ev[e * 3 + 1];
        evp[p * 3 + 2] = ev[e * 3 + 2];
    }
}

// ---------------------------------------------------------------------------
// Layer 0: 128-edge blocks, 4 edges/lane (r10-proven, bit-identical to r8).
// ---------------------------------------------------------------------------
__launch_bounds__(256, 3)
__global__ void layer0_edge(const float* __restrict__ evp, const int* __restrict__ srcs,
                            const int* __restrict__ xs, const float* __restrict__ embw,
                            const float* __restrict__ w1, const float* __restrict__ b1,
                            const float* __restrict__ w2, const float* __restrict__ b2,
                            float* __restrict__ mbuf)
{
    __shared__ float emb_s[128 * 17];
    __shared__ float hid_s[128 * 68];
    __shared__ float w2t[24 * 68];
    const int tid = threadIdx.x;
    const int e0 = blockIdx.x * 128;

    for (int idx = tid; idx < 64 * 24; idx += 256) {
        int j = idx / 24, o = idx - j * 24;
        w2t[o * 68 + j] = w2[idx];
    }
    for (int idx = tid; idx < 2048; idx += 256) {
        int e = idx >> 4, i = idx & 15;
        const float* ep = evp + (size_t)(e0 + e) * 3;
        float ex = ep[0], ey = ep[1], ez = ep[2];
        float r = sqrtf(ex * ex + ey * ey + ez * ez + 1e-12f);
        float d = r * (17.0f / 3.0f) - (float)(i + 1);
        float f = 0.0f;
        if (fabsf(d) < 1.0f) f = 8.433572869f * __expf(-2.0f / (1.0f - d * d));
        emb_s[e * 17 + i] = f;
    }
    __syncthreads();

    {
        const int egp = tid >> 3;
        const int jb = (tid & 7) * 8;
        float acc2[4][8];
        #pragma unroll
        for (int el = 0; el < 4; ++el)
            #pragma unroll
            for (int k = 0; k < 8; ++k) acc2[el][k] = b1[jb + k];
        #pragma unroll
        for (int i = 0; i < 16; ++i) {
            float4 wa = *(const float4*)&w1[i * 64 + jb];
            float4 wb = *(const float4*)&w1[i * 64 + jb + 4];
            #pragma unroll
            for (int el = 0; el < 4; ++el) {
                float evv = emb_s[(egp * 4 + el) * 17 + i];
                acc2[el][0] += evv * wa.x; acc2[el][1] += evv * wa.y;
                acc2[el][2] += evv * wa.z; acc2[el][3] += evv * wa.w;
                acc2[el][4] += evv * wb.x; acc2[el][5] += evv * wb.y;
                acc2[el][6] += evv * wb.z; acc2[el][7] += evv * wb.w;
            }
        }
        #pragma unroll
        for (int el = 0; el < 4; ++el)
            #pragma unroll
            for (int k = 0; k < 8; ++k)
                hid_s[(egp * 4 + el) * 68 + jb + k] = silu_f(acc2[el][k]);
    }
    __syncthreads();

    const int c = tid & 7, g = (tid >> 3) & 7, wv_ = tid >> 6;
    float wacc[3][4];
    #pragma unroll
    for (int p = 0; p < 3; ++p) {
        float bb = b2[p * 8 + c];
        #pragma unroll
        for (int q = 0; q < 4; ++q) wacc[p][q] = bb;
    }
    for (int jb = 0; jb < 64; jb += 4) {
        float4 h4[4];
        #pragma unroll
        for (int q = 0; q < 4; ++q)
            h4[q] = *(const float4*)&hid_s[(wv_ * 32 + q * 8 + g) * 68 + jb];
        #pragma unroll
        for (int p = 0; p < 3; ++p) {
            float4 w4 = *(const float4*)&w2t[(p * 8 + c) * 68 + jb];
            #pragma unroll
            for (int q = 0; q < 4; ++q)
                wacc[p][q] += h4[q].x * w4.x + h4[q].y * w4.y + h4[q].z * w4.z + h4[q].w * w4.w;
        }
    }

    const int ebase = wv_ * 32 + g;
    const float c3 = 1.7320508f, c15 = 3.8729833f, c5 = 2.2360680f;
    #pragma unroll
    for (int q = 0; q < 4; ++q) {
        const int sl = e0 + ebase + 8 * q;
        const int sn = srcs[sl];
        float hs = embw[xs[sn] * 8 + c];
        const float* ep = evp + (size_t)sl * 3;
        float ex = ep[0], ey = ep[1], ez = ep[2];
        float r = sqrtf(ex * ex + ey * ey + ez * ez + 1e-12f);
        float inv = 1.0f / r;
        float x = ex * inv, y = ey * inv, z = ez * inv;

        float* me = mbuf + (size_t)sl * 72 + c * 9;
        me[0] = wacc[0][q] * hs;
        me[1] = wacc[1][q] * hs * (c3 * y);
        me[2] = wacc[1][q] * hs * (c3 * z);
        me[3] = wacc[1][q] * hs * (c3 * x);
        me[4] = wacc[2][q] * hs * (c15 * x * y);
        me[5] = wacc[2][q] * hs * (c15 * y * z);
        me[6] = wacc[2][q] * hs * (0.5f * c5 * (3.f * z * z - 1.f));
        me[7] = wacc[2][q] * hs * (c15 * x * z);
        me[8] = wacc[2][q] * hs * (0.5f * c15 * (x * x - y * y));
    }
}

// ---------------------------------------------------------------------------
// Layers 1/2: pk-fp32 tp_edge, two-pass w2t staging (LDS 35.7 KB -> 4 blk/CU)
// with launch_bounds(256,3): loose register bound (<=170) so the allocator
// reproduces r10's 80-VGPR no-spill phase D (r11's (256,4) forced VGPR=64 ->
// catastrophic scratch spill, FETCH 195MB->3.9GB). Occupancy then comes from
// LDS: 4 blocks/CU, 16 waves. acc visits jb ascending -> bit-identical.
// ---------------------------------------------------------------------------
__launch_bounds__(256, 3)
__global__ void tp_edge(const float* __restrict__ evp, const int* __restrict__ srcs,
                        const float* __restrict__ h,
                        const float* __restrict__ w1, const float* __restrict__ b1,
                        const float* __restrict__ w2, const float* __restrict__ b2,
                        float* __restrict__ mbuf)
{
    __shared__ float w2t[120 * 36];            // 17,280 B; emb_s aliased (needs 8,704)
    __shared__ unsigned short hid_s[128 * 72]; // 18,432 B
    float* emb_s = w2t;

    const int tid = threadIdx.x;
    const int e0 = blockIdx.x * 128;

    // Phase A: soft one-hot -> emb_s[e*17+i]
    for (int idx = tid; idx < 2048; idx += 256) {
        int e = idx >> 4, i = idx & 15;
        const float* ep = evp + (size_t)(e0 + e) * 3;
        float ex = ep[0], ey = ep[1], ez = ep[2];
        float r = sqrtf(ex * ex + ey * ey + ez * ez + 1e-12f);
        float d = r * (17.0f / 3.0f) - (float)(i + 1);
        float f = 0.0f;
        if (fabsf(d) < 1.0f) f = 8.433572869f * __expf(-2.0f / (1.0f - d * d));
        emb_s[e * 17 + i] = f;
    }
    __syncthreads();

    // Phase B: hidden = silu(emb @ w1 + b1), 4 edges/thread packed as 2 pairs
    {
        const int egp = tid >> 3;
        const int jb = (tid & 7) * 8;
        f32x2v acc2[2][8];
        #pragma unroll
        for (int pr = 0; pr < 2; ++pr)
            #pragma unroll
            for (int k = 0; k < 8; ++k) { float bb = b1[jb + k]; acc2[pr][k] = mk2(bb, bb); }
        #pragma unroll
        for (int i = 0; i < 16; ++i) {
            float4 wa = *(const float4*)&w1[i * 64 + jb];
            float4 wb = *(const float4*)&w1[i * 64 + jb + 4];
            #pragma unroll
            for (int pr = 0; pr < 2; ++pr) {
                f32x2v evv = mk2(emb_s[(egp * 4 + 2 * pr) * 17 + i],
                                 emb_s[(egp * 4 + 2 * pr + 1) * 17 + i]);
                acc2[pr][0] += evv * wa.x; acc2[pr][1] += evv * wa.y;
                acc2[pr][2] += evv * wa.z; acc2[pr][3] += evv * wa.w;
                acc2[pr][4] += evv * wb.x; acc2[pr][5] += evv * wb.y;
                acc2[pr][6] += evv * wb.z; acc2[pr][7] += evv * wb.w;
            }
        }
        #pragma unroll
        for (int pr = 0; pr < 2; ++pr) {
            #pragma unroll
            for (int u = 0; u < 2; ++u) {
                unsigned int us[8];
                #pragma unroll
                for (int k = 0; k < 8; ++k) {
                    unsigned int b = __float_as_uint(silu_f(acc2[pr][k][u]));
                    b += 0x7fffu + ((b >> 16) & 1u);
                    us[k] = b >> 16;
                }
                uint4 pk;
                pk.x = us[0] | (us[1] << 16);
                pk.y = us[2] | (us[3] << 16);
                pk.z = us[4] | (us[5] << 16);
                pk.w = us[6] | (us[7] << 16);
                *(uint4*)&hid_s[(egp * 4 + 2 * pr + u) * 72 + jb] = pk;
            }
        }
    }

    // Phase C/D: two K-column passes; acc order = jb ascending (bit-identical)
    const int c = tid & 7, g = (tid >> 3) & 7, wv_ = tid >> 6;
    f32x2v acc[15][2];
    #pragma unroll
    for (int p = 0; p < 15; ++p) {
        float bb = b2[p * 8 + c];
        acc[p][0] = mk2(bb, bb);
        acc[p][1] = mk2(bb, bb);
    }

    #pragma unroll
    for (int half = 0; half < 2; ++half) {
        const int col0 = half * 32;
        __syncthreads();   // half0: emb reads done; half1: D-half0 w2t reads done
        for (int idx = tid; idx < 32 * 120; idx += 256) {
            int j = idx / 120, o = idx - j * 120;      // j in 0..31
            w2t[o * 36 + j] = w2[(col0 + j) * 120 + o];
        }
        __syncthreads();

        for (int jb = 0; jb < 32; jb += 8) {
            f32x2v hf[8][2];
            #pragma unroll
            for (int pr = 0; pr < 2; ++pr) {
                uint4 h0 = *(const uint4*)&hid_s[(wv_ * 32 + (2 * pr) * 8 + g) * 72 + col0 + jb];
                uint4 h1 = *(const uint4*)&hid_s[(wv_ * 32 + (2 * pr + 1) * 8 + g) * 72 + col0 + jb];
                hf[0][pr] = mk2(__uint_as_float(h0.x << 16),        __uint_as_float(h1.x << 16));
                hf[1][pr] = mk2(__uint_as_float(h0.x & 0xffff0000u), __uint_as_float(h1.x & 0xffff0000u));
                hf[2][pr] = mk2(__uint_as_float(h0.y << 16),        __uint_as_float(h1.y << 16));
                hf[3][pr] = mk2(__uint_as_float(h0.y & 0xffff0000u), __uint_as_float(h1.y & 0xffff0000u));
                hf[4][pr] = mk2(__uint_as_float(h0.z << 16),        __uint_as_float(h1.z << 16));
                hf[5][pr] = mk2(__uint_as_float(h0.z & 0xffff0000u), __uint_as_float(h1.z & 0xffff0000u));
                hf[6][pr] = mk2(__uint_as_float(h0.w << 16),        __uint_as_float(h1.w << 16));
                hf[7][pr] = mk2(__uint_as_float(h0.w & 0xffff0000u), __uint_as_float(h1.w & 0xffff0000u));
            }
            #pragma unroll
            for (int p = 0; p < 15; ++p) {
                float4 wa = *(const float4*)&w2t[(p * 8 + c) * 36 + jb];
                float4 wb = *(const float4*)&w2t[(p * 8 + c) * 36 + jb + 4];
                #pragma unroll
                for (int pr = 0; pr < 2; ++pr) {
                    acc[p][pr] += hf[0][pr] * wa.x + hf[1][pr] * wa.y + hf[2][pr] * wa.z + hf[3][pr] * wa.w
                                + hf[4][pr] * wb.x + hf[5][pr] * wb.y + hf[6][pr] * wb.z + hf[7][pr] * wb.w;
                }
            }
        }
    }

    // Tail: 2 pairs of edges, packed tp_uuu; gathers hoisted per pair
    const int ebase = wv_ * 32 + g;
    int sn[4];
    #pragma unroll
    for (int q = 0; q < 4; ++q) sn[q] = srcs[e0 + ebase + 8 * q];

    #pragma unroll
    for (int hh = 0; hh < 2; ++hh) {
        const float* hn0 = h + (size_t)sn[2 * hh] * 72 + c * 9;
        const float* hn1 = h + (size_t)sn[2 * hh + 1] * 72 + c * 9;
        const float* me0 = mbuf + (size_t)(e0 + ebase + 8 * (2 * hh)) * 72 + c * 9;
        const float* me1 = mbuf + (size_t)(e0 + ebase + 8 * (2 * hh + 1)) * 72 + c * 9;

        f32x2v as = mk2(hn0[0], hn1[0]);
        f32x2v av[3], at[5], bv[3], bt[5];
        #pragma unroll
        for (int i = 0; i < 3; ++i) av[i] = mk2(hn0[1 + i], hn1[1 + i]);
        #pragma unroll
        for (int i = 0; i < 5; ++i) at[i] = mk2(hn0[4 + i], hn1[4 + i]);
        f32x2v bs = mk2(silu_f(me0[0]), silu_f(me1[0]));
        #pragma unroll
        for (int i = 0; i < 3; ++i) bv[i] = mk2(me0[1 + i], me1[1 + i]);
        #pragma unroll
        for (int i = 0; i < 5; ++i) bt[i] = mk2(me0[4 + i], me1[4 + i]);

        f32x2v wvv[15];
        #pragma unroll
        for (int p = 0; p < 15; ++p) wvv[p] = acc[p][hh];

        f32x2v ms, mv[3], mt[5];
        tp_uuu2(wvv, as, av, at, bs, bv, bt, ms, mv, mt);

        float* mo0 = mbuf + (size_t)(e0 + ebase + 8 * (2 * hh)) * 72 + c * 9;
        float* mo1 = mbuf + (size_t)(e0 + ebase + 8 * (2 * hh + 1)) * 72 + c * 9;
        mo0[0] = ms[0]; mo1[0] = ms[1];
        #pragma unroll
        for (int i = 0; i < 3; ++i) { mo0[1 + i] = mv[i][0]; mo1[1 + i] = mv[i][1]; }
        #pragma unroll
        for (int i = 0; i < 5; ++i) { mo0[4 + i] = mt[i][0]; mo1[4 + i] = mt[i][1]; }
    }
}

// ---------------------------------------------------------------------------
// Node updates: sequential CSR-span gather of slot-ordered mbuf
// ---------------------------------------------------------------------------
__global__ void node0(const int* __restrict__ xs, const float* __restrict__ embw,
                      const float* __restrict__ lin0, const float* __restrict__ mbuf,
                      const int* __restrict__ off, float* __restrict__ h)
{
    int idx = blockIdx.x * 256 + threadIdx.x;
    int n = idx >> 3, c = idx & 7;
    int xb = xs[n] * 8;
    float dot = 0.f;
    #pragma unroll
    for (int d = 0; d < 8; ++d) dot += embw[xb + d] * lin0[d * 8 + c];

    float an[9];
    #pragma unroll
    for (int i = 0; i < 9; ++i) an[i] = 0.f;
    const int beg = off[n], end = off[n + 1];
    for (int p = beg; p < end; ++p) {
        const float* me = mbuf + (size_t)p * 72 + c * 9;
        #pragma unroll
        for (int i = 0; i < 9; ++i) an[i] += me[i];
    }

    float* hn = h + (size_t)n * 72 + c * 9;
    hn[0] = silu_f(an[0] * 0.25f + dot * 0.35355339f);
    #pragma unroll
    for (int i = 1; i < 9; ++i) hn[i] = an[i] * 0.25f;
}

__global__ void node12(const float* __restrict__ hin, const float* __restrict__ lin,
                       const float* __restrict__ mbuf, const int* __restrict__ off,
                       float* __restrict__ hout)
{
    int idx = blockIdx.x * 256 + threadIdx.x;
    int n = idx >> 3, d = idx & 7;

    float an[9];
    #pragma unroll
    for (int i = 0; i < 9; ++i) an[i] = 0.f;
    const int beg = off[n], end = off[n + 1];
    for (int p = beg; p < end; ++p) {
        const float* me = mbuf + (size_t)p * 72 + d * 9;
        #pragma unroll
        for (int i = 0; i < 9; ++i) an[i] += me[i];
    }

    const float* hn = hin + (size_t)n * 72;
    float* ho = hout + (size_t)n * 72 + d * 9;

    float s = 0.f;
    #pragma unroll
    for (int c = 0; c < 8; ++c) s += hn[c * 9] * lin[c * 8 + d];
    ho[0] = silu_f(s * 0.35355339f + an[0] * 0.25f);
    #pragma unroll
    for (int i = 0; i < 3; ++i) {
        float v = 0.f;
        #pragma unroll
        for (int c = 0; c < 8; ++c) v += hn[c * 9 + 1 + i] * lin[64 + c * 8 + d];
        ho[1 + i] = v * 0.35355339f + an[1 + i] * 0.25f;
    }
    #pragma unroll
    for (int i = 0; i < 5; ++i) {
        float t = 0.f;
        #pragma unroll
        for (int c = 0; c < 8; ++c) t += hn[c * 9 + 4 + i] * lin[128 + c * 8 + d];
        ho[4 + i] = t * 0.35355339f + an[4 + i] * 0.25f;
    }
}

// Fused final node update + output head: h record staged in LDS, never HBM
__global__ void node12_out(const float* __restrict__ hin, const float* __restrict__ lin,
                           const float* __restrict__ mbuf, const int* __restrict__ off,
                           const float* __restrict__ outw, float* __restrict__ out)
{
    __shared__ float hrec[32][72];
    int idx = blockIdx.x * 256 + threadIdx.x;
    int n = idx >> 3, d = idx & 7;
    int nl = threadIdx.x >> 3;

    float an[9];
    #pragma unroll
    for (int i = 0; i < 9; ++i) an[i] = 0.f;
    const int beg = off[n], end = off[n + 1];
    for (int p = beg; p < end; ++p) {
        const float* me = mbuf + (size_t)p * 72 + d * 9;
        #pragma unroll
        for (int i = 0; i < 9; ++i) an[i] += me[i];
    }

    const float* hn = hin + (size_t)n * 72;
    float* ho = &hrec[nl][d * 9];

    float s = 0.f;
    #pragma unroll
    for (int c = 0; c < 8; ++c) s += hn[c * 9] * lin[c * 8 + d];
    ho[0] = silu_f(s * 0.35355339f + an[0] * 0.25f);
    #pragma unroll
    for (int i = 0; i < 3; ++i) {
        float v = 0.f;
        #pragma unroll
        for (int c = 0; c < 8; ++c) v += hn[c * 9 + 1 + i] * lin[64 + c * 8 + d];
        ho[1 + i] = v * 0.35355339f + an[1 + i] * 0.25f;
    }
    #pragma unroll
    for (int i = 0; i < 5; ++i) {
        float t = 0.f;
        #pragma unroll
        for (int c = 0; c < 8; ++c) t += hn[c * 9 + 4 + i] * lin[128 + c * 8 + d];
        ho[4 + i] = t * 0.35355339f + an[4 + i] * 0.25f;
    }
    __syncthreads();

    const float* hr = &hrec[nl][0];
    float sv[8], vv[24], tv[40];
    #pragma unroll
    for (int i = 0; i < 8; ++i) {
        sv[i] = hr[i * 9];
        #pragma unroll
        for (int q = 0; q < 3; ++q) vv[i * 3 + q] = hr[i * 9 + 1 + q];
        #pragma unroll
        for (int q = 0; q < 5; ++q) tv[i * 5 + q] = hr[i * 9 + 4 + q];
    }
    float acc = 0.f;
    #pragma unroll
    for (int i = 0; i < 8; ++i) {
        #pragma unroll
        for (int j = 0; j < 8; ++j) {
            float dv = vv[i*3+0]*vv[j*3+0] + vv[i*3+1]*vv[j*3+1] + vv[i*3+2]*vv[j*3+2];
            float dt = tv[i*5+0]*tv[j*5+0] + tv[i*5+1]*tv[j*5+1] + tv[i*5+2]*tv[j*5+2]
                     + tv[i*5+3]*tv[j*5+3] + tv[i*5+4]*tv[j*5+4];
            int o = (i * 8 + j) * 8 + d;
            acc += sv[i] * sv[j] * outw[o]
                 + dv * 0.57735027f * outw[512 + o]
                 + dt * 0.44721360f * outw[1024 + o];
        }
    }
    out[n * 8 + d] = acc * 0.072168784f;
}

// ---------------------------------------------------------------------------
extern "C" void kernel_launch(void* const* d_in, const int* in_sizes, int n_in,
                              void* d_out, int out_size, void* d_ws, size_t ws_size,
                              hipStream_t stream)
{
    const int*   x    = (const int*)  d_in[0];
    const int*   eidx = (const int*)  d_in[1];
    const float* ev   = (const float*)d_in[2];
    const float* embw = (const float*)d_in[3];
    const float* lin0 = (const float*)d_in[4];
    const float* lin1 = (const float*)d_in[5];
    const float* lin2 = (const float*)d_in[6];
    const float* outw = (const float*)d_in[7];
    const float* r0w1 = (const float*)d_in[8];
    const float* r0b1 = (const float*)d_in[9];
    const float* r0w2 = (const float*)d_in[10];
    const float* r0b2 = (const float*)d_in[11];
    const float* r1w1 = (const float*)d_in[12];
    const float* r1b1 = (const float*)d_in[13];
    const float* r1w2 = (const float*)d_in[14];
    const float* r1b2 = (const float*)d_in[15];
    const float* r2w1 = (const float*)d_in[16];
    const float* r2b1 = (const float*)d_in[17];
    const float* r2w2 = (const float*)d_in[18];
    const float* r2b2 = (const float*)d_in[19];

    float* mbuf = (float*)d_ws;                          // EDGES*72 f32
    float* hA   = mbuf + (size_t)EDGES * 72;             // NODES*72
    float* hB   = hA + (size_t)NODES * 72;               // NODES*72
    float* evp  = hB + (size_t)NODES * 72;               // EDGES*3
    int*   deg    = (int*)(evp + (size_t)EDGES * 3);     // NODES
    int*   off    = deg + NODES;                         // NODES+1
    int*   cursor = off + NODES + 1;                     // NODES
    int*   srcs   = cursor + NODES;                      // EDGES

    const int EBI = (EDGES + 255) / 256;
    const int EB  = EDGES / 128;
    const int NBK = NODES * 8 / 256;

    // CSR build + fused permutation
    hipMemsetAsync(deg, 0, NODES * sizeof(int), stream);
    deg_kernel<<<EBI, 256, 0, stream>>>(eidx, deg);
    scan_kernel<<<1, 1024, 0, stream>>>(deg, off, cursor);
    build_kernel<<<EBI, 256, 0, stream>>>(eidx, ev, cursor, evp, srcs);

    // Layer 0
    layer0_edge<<<EB, 256, 0, stream>>>(evp, srcs, x, embw, r0w1, r0b1, r0w2, r0b2, mbuf);
    node0<<<NBK, 256, 0, stream>>>(x, embw, lin0, mbuf, off, hA);

    // Layer 1
    tp_edge<<<EB, 256, 0, stream>>>(evp, srcs, hA, r1w1, r1b1, r1w2, r1b2, mbuf);
    node12<<<NBK, 256, 0, stream>>>(hA, lin1, mbuf, off, hB);

    // Layer 2 + output head (fused)
    tp_edge<<<EB, 256, 0, stream>>>(evp, srcs, hB, r2w1, r2b1, r2w2, r2b2, mbuf);
    node12_out<<<NBK, 256, 0, stream>>>(hB, lin2, mbuf, off, outw, (float*)d_out);
}

// Round 13
// 827.633 us; speedup vs baseline: 6.1018x; 5.0242x over previous
//
#include <hip/hip_runtime.h>

#define NODES 40000
#define EDGES 640000

typedef float f32x2v __attribute__((ext_vector_type(2)));

__device__ __forceinline__ float silu_f(float x) { return x / (1.0f + __expf(-x)); }
__device__ __forceinline__ f32x2v mk2(float a, float b) { f32x2v r; r[0] = a; r[1] = b; return r; }

// ---------------------------------------------------------------------------
// Real-basis Clebsch-Gordan contraction, 2 edges packed per call (f32x2v).
// Per-edge op sequence identical to the validated scalar version.
// v: [y,z,x] ; t: [xy,yz,z2,xz,x2y2]
// ---------------------------------------------------------------------------
__device__ __forceinline__ void tp_uuu2(const f32x2v* wv,
                                        f32x2v as, const f32x2v* av, const f32x2v* at,
                                        f32x2v bs, const f32x2v* bv, const f32x2v* bt,
                                        f32x2v& ms, f32x2v* mv, f32x2v* mt)
{
    const float CR = 0.70710678f;
    const float K1 = 0.31622777f;
    const float K3 = 0.54772256f;
    const float KA = 0.40824829f;
    const float KB = 0.70710678f;
    const float KC = 0.81649658f;
    const float L4 = 0.63245553f;
    const float G2 = 0.53452248f;
    const float G1 = 0.26726124f;
    const float HH = 0.46291005f;

    f32x2v os = {0.f, 0.f};
    f32x2v ov0 = {0.f, 0.f}, ov1 = {0.f, 0.f}, ov2 = {0.f, 0.f};
    f32x2v ot0 = {0.f, 0.f}, ot1 = {0.f, 0.f}, ot2 = {0.f, 0.f};
    f32x2v ot3 = {0.f, 0.f}, ot4 = {0.f, 0.f};

    os += wv[0] * as * bs;
    ov0 += wv[1] * as * bv[0]; ov1 += wv[1] * as * bv[1]; ov2 += wv[1] * as * bv[2];
    ot0 += wv[2] * as * bt[0]; ot1 += wv[2] * as * bt[1]; ot2 += wv[2] * as * bt[2];
    ot3 += wv[2] * as * bt[3]; ot4 += wv[2] * as * bt[4];
    ov0 += wv[3] * av[0] * bs; ov1 += wv[3] * av[1] * bs; ov2 += wv[3] * av[2] * bs;
    os += wv[4] * (-0.57735027f) * (av[0]*bv[0] + av[1]*bv[1] + av[2]*bv[2]);
    ov0 += wv[5] * CR * (av[1]*bv[2] - av[2]*bv[1]);
    ov1 += wv[5] * CR * (av[2]*bv[0] - av[0]*bv[2]);
    ov2 += wv[5] * CR * (av[0]*bv[1] - av[1]*bv[0]);
    ot0 += wv[6] * CR * (av[2]*bv[0] + av[0]*bv[2]);
    ot1 += wv[6] * CR * (av[0]*bv[1] + av[1]*bv[0]);
    ot2 += wv[6] * 0.40824829f * (2.f*av[1]*bv[1] - av[2]*bv[2] - av[0]*bv[0]);
    ot3 += wv[6] * CR * (av[2]*bv[1] + av[1]*bv[2]);
    ot4 += wv[6] * CR * (av[2]*bv[2] - av[0]*bv[0]);
    ov0 += wv[7] * (-K3*av[1]*bt[1] + K1*av[0]*bt[2] - K3*av[2]*bt[0] + K3*av[0]*bt[4]);
    ov1 += wv[7] * (-2.f*K1*av[1]*bt[2] - K3*av[2]*bt[3] - K3*av[0]*bt[1]);
    ov2 += wv[7] * (-K3*av[1]*bt[3] + K1*av[2]*bt[2] - K3*av[0]*bt[0] - K3*av[2]*bt[4]);
    ot0 += wv[8] * ( KC*av[1]*bt[4] - KA*av[2]*bt[3] + KA*av[0]*bt[1]);
    ot1 += wv[8] * ( KA*av[1]*bt[3] - KB*av[2]*bt[2] - KA*av[0]*bt[0] - KA*av[2]*bt[4]);
    ot2 += wv[8] * ( KB*av[2]*bt[1] - KB*av[0]*bt[3]);
    ot3 += wv[8] * (-KA*av[1]*bt[1] + KB*av[0]*bt[2] + KA*av[2]*bt[0] - KA*av[0]*bt[4]);
    ot4 += wv[8] * (-KC*av[1]*bt[0] + KA*av[2]*bt[1] + KA*av[0]*bt[3]);
    ot0 += wv[9] * at[0] * bs; ot1 += wv[9] * at[1] * bs; ot2 += wv[9] * at[2] * bs;
    ot3 += wv[9] * at[3] * bs; ot4 += wv[9] * at[4] * bs;
    ov0 += wv[10] * (-K3*bv[1]*at[1] + K1*bv[0]*at[2] - K3*bv[2]*at[0] + K3*bv[0]*at[4]);
    ov1 += wv[10] * (-2.f*K1*bv[1]*at[2] - K3*bv[2]*at[3] - K3*bv[0]*at[1]);
    ov2 += wv[10] * (-K3*bv[1]*at[3] + K1*bv[2]*at[2] - K3*bv[0]*at[0] - K3*bv[2]*at[4]);
    ot0 -= wv[11] * ( KC*bv[1]*at[4] - KA*bv[2]*at[3] + KA*bv[0]*at[1]);
    ot1 -= wv[11] * ( KA*bv[1]*at[3] - KB*bv[2]*at[2] - KA*bv[0]*at[0] - KA*bv[2]*at[4]);
    ot2 -= wv[11] * ( KB*bv[2]*at[1] - KB*bv[0]*at[3]);
    ot3 -= wv[11] * (-KA*bv[1]*at[1] + KB*bv[0]*at[2] + KA*bv[2]*at[0] - KA*bv[0]*at[4]);
    ot4 -= wv[11] * (-KC*bv[1]*at[0] + KA*bv[2]*at[1] + KA*bv[0]*at[3]);
    os += wv[12] * 0.44721360f * (at[0]*bt[0] + at[1]*bt[1] + at[2]*bt[2] + at[3]*bt[3] + at[4]*bt[4]);
    ov0 += wv[13] * ( K1*(at[0]*bt[1] - at[1]*bt[0]) + K3*(at[3]*bt[2] - at[2]*bt[3]) + K1*(at[4]*bt[3] - at[3]*bt[4]) );
    ov1 += wv[13] * ( L4*(at[0]*bt[4] - at[4]*bt[0]) + K1*(at[1]*bt[3] - at[3]*bt[1]) );
    ov2 += wv[13] * ( K1*(at[3]*bt[0] - at[0]*bt[3]) + K3*(at[2]*bt[1] - at[1]*bt[2]) + K1*(at[4]*bt[1] - at[1]*bt[4]) );
    ot0 += wv[14] * ( G2*(at[2]*bt[0] + at[0]*bt[2]) - HH*(at[1]*bt[3] + at[3]*bt[1]) );
    ot1 += wv[14] * (-HH*(at[3]*bt[0] + at[0]*bt[3]) + HH*(at[1]*bt[4] + at[4]*bt[1]) - G1*(at[2]*bt[1] + at[1]*bt[2]) );
    ot2 += wv[14] * ( G2*(at[0]*bt[0] + at[4]*bt[4] - at[2]*bt[2]) - G1*(at[1]*bt[1] + at[3]*bt[3]) );
    ot3 += wv[14] * (-HH*(at[1]*bt[0] + at[0]*bt[1]) - HH*(at[3]*bt[4] + at[4]*bt[3]) - G1*(at[2]*bt[3] + at[3]*bt[2]) );
    ot4 += wv[14] * ( G2*(at[2]*bt[4] + at[4]*bt[2]) + HH*(at[1]*bt[1] - at[3]*bt[3]) );

    ms = os * 0.57735027f;
    mv[0] = ov0 * 0.40824829f; mv[1] = ov1 * 0.40824829f; mv[2] = ov2 * 0.40824829f;
    mt[0] = ot0 * 0.40824829f; mt[1] = ot1 * 0.40824829f; mt[2] = ot2 * 0.40824829f;
    mt[3] = ot3 * 0.40824829f; mt[4] = ot4 * 0.40824829f;
}

// ---------------------------------------------------------------------------
// CSR construction + fused permutation (slot order = dst-sorted)
// ---------------------------------------------------------------------------
__global__ void deg_kernel(const int* __restrict__ eidx, int* __restrict__ deg)
{
    int e = blockIdx.x * 256 + threadIdx.x;
    if (e < EDGES) atomicAdd(&deg[eidx[EDGES + e]], 1);
}

__launch_bounds__(1024)
__global__ void scan_kernel(const int* __restrict__ deg, int* __restrict__ off,
                            int* __restrict__ cursor)
{
    __shared__ int part[1024];
    const int t = threadIdx.x;
    const int base = t * 40;     // threads 0..999 cover exactly 40000
    int v[40];
    if (t < 1000) {
        const int4* p4 = (const int4*)(deg + base);
        #pragma unroll
        for (int i = 0; i < 10; ++i) {
            int4 q = p4[i];
            v[4 * i + 0] = q.x; v[4 * i + 1] = q.y;
            v[4 * i + 2] = q.z; v[4 * i + 3] = q.w;
        }
    } else {
        #pragma unroll
        for (int i = 0; i < 40; ++i) v[i] = 0;
    }
    int loc[40];
    int s = 0;
    #pragma unroll
    for (int i = 0; i < 40; ++i) { loc[i] = s; s += v[i]; }
    part[t] = s;
    __syncthreads();
    for (int d = 1; d < 1024; d <<= 1) {
        int vv = (t >= d) ? part[t - d] : 0;
        __syncthreads();
        part[t] += vv;
        __syncthreads();
    }
    int tb = (t == 0) ? 0 : part[t - 1];
    if (t < 1000) {
        #pragma unroll
        for (int i = 0; i < 40; ++i) {
            off[base + i] = tb + loc[i];
            cursor[base + i] = tb + loc[i];
        }
    }
    if (t == 1023) off[NODES] = part[1023];
}

// build + permute fused: scatter srcs/evp into CSR slot order directly
__global__ void build_kernel(const int* __restrict__ eidx, const float* __restrict__ ev,
                             int* __restrict__ cursor,
                             float* __restrict__ evp, int* __restrict__ srcs)
{
    int e = blockIdx.x * 256 + threadIdx.x;
    if (e < EDGES) {
        int dst = eidx[EDGES + e];
        int p = atomicAdd(&cursor[dst], 1);
        srcs[p] = eidx[e];
        evp[p * 3 + 0] = ev[e * 3 + 0];
        evp[p * 3 + 1] = ev[e * 3 + 1];
        evp[p * 3 + 2] = ev[e * 3 + 2];
    }
}

// ---------------------------------------------------------------------------
// Layer 0: 128-edge blocks, 4 edges/lane (r10-proven, bit-identical to r8).
// ---------------------------------------------------------------------------
__launch_bounds__(256, 3)
__global__ void layer0_edge(const float* __restrict__ evp, const int* __restrict__ srcs,
                            const int* __restrict__ xs, const float* __restrict__ embw,
                            const float* __restrict__ w1, const float* __restrict__ b1,
                            const float* __restrict__ w2, const float* __restrict__ b2,
                            float* __restrict__ mbuf)
{
    __shared__ float emb_s[128 * 17];
    __shared__ float hid_s[128 * 68];
    __shared__ float w2t[24 * 68];
    const int tid = threadIdx.x;
    const int e0 = blockIdx.x * 128;

    for (int idx = tid; idx < 64 * 24; idx += 256) {
        int j = idx / 24, o = idx - j * 24;
        w2t[o * 68 + j] = w2[idx];
    }
    for (int idx = tid; idx < 2048; idx += 256) {
        int e = idx >> 4, i = idx & 15;
        const float* ep = evp + (size_t)(e0 + e) * 3;
        float ex = ep[0], ey = ep[1], ez = ep[2];
        float r = sqrtf(ex * ex + ey * ey + ez * ez + 1e-12f);
        float d = r * (17.0f / 3.0f) - (float)(i + 1);
        float f = 0.0f;
        if (fabsf(d) < 1.0f) f = 8.433572869f * __expf(-2.0f / (1.0f - d * d));
        emb_s[e * 17 + i] = f;
    }
    __syncthreads();

    {
        const int egp = tid >> 3;
        const int jb = (tid & 7) * 8;
        float acc2[4][8];
        #pragma unroll
        for (int el = 0; el < 4; ++el)
            #pragma unroll
            for (int k = 0; k < 8; ++k) acc2[el][k] = b1[jb + k];
        #pragma unroll
        for (int i = 0; i < 16; ++i) {
            float4 wa = *(const float4*)&w1[i * 64 + jb];
            float4 wb = *(const float4*)&w1[i * 64 + jb + 4];
            #pragma unroll
            for (int el = 0; el < 4; ++el) {
                float evv = emb_s[(egp * 4 + el) * 17 + i];
                acc2[el][0] += evv * wa.x; acc2[el][1] += evv * wa.y;
                acc2[el][2] += evv * wa.z; acc2[el][3] += evv * wa.w;
                acc2[el][4] += evv * wb.x; acc2[el][5] += evv * wb.y;
                acc2[el][6] += evv * wb.z; acc2[el][7] += evv * wb.w;
            }
        }
        #pragma unroll
        for (int el = 0; el < 4; ++el)
            #pragma unroll
            for (int k = 0; k < 8; ++k)
                hid_s[(egp * 4 + el) * 68 + jb + k] = silu_f(acc2[el][k]);
    }
    __syncthreads();

    const int c = tid & 7, g = (tid >> 3) & 7, wv_ = tid >> 6;
    float wacc[3][4];
    #pragma unroll
    for (int p = 0; p < 3; ++p) {
        float bb = b2[p * 8 + c];
        #pragma unroll
        for (int q = 0; q < 4; ++q) wacc[p][q] = bb;
    }
    for (int jb = 0; jb < 64; jb += 4) {
        float4 h4[4];
        #pragma unroll
        for (int q = 0; q < 4; ++q)
            h4[q] = *(const float4*)&hid_s[(wv_ * 32 + q * 8 + g) * 68 + jb];
        #pragma unroll
        for (int p = 0; p < 3; ++p) {
            float4 w4 = *(const float4*)&w2t[(p * 8 + c) * 68 + jb];
            #pragma unroll
            for (int q = 0; q < 4; ++q)
                wacc[p][q] += h4[q].x * w4.x + h4[q].y * w4.y + h4[q].z * w4.z + h4[q].w * w4.w;
        }
    }

    const int ebase = wv_ * 32 + g;
    const float c3 = 1.7320508f, c15 = 3.8729833f, c5 = 2.2360680f;
    #pragma unroll
    for (int q = 0; q < 4; ++q) {
        const int sl = e0 + ebase + 8 * q;
        const int sn = srcs[sl];
        float hs = embw[xs[sn] * 8 + c];
        const float* ep = evp + (size_t)sl * 3;
        float ex = ep[0], ey = ep[1], ez = ep[2];
        float r = sqrtf(ex * ex + ey * ey + ez * ez + 1e-12f);
        float inv = 1.0f / r;
        float x = ex * inv, y = ey * inv, z = ez * inv;

        float* me = mbuf + (size_t)sl * 72 + c * 9;
        me[0] = wacc[0][q] * hs;
        me[1] = wacc[1][q] * hs * (c3 * y);
        me[2] = wacc[1][q] * hs * (c3 * z);
        me[3] = wacc[1][q] * hs * (c3 * x);
        me[4] = wacc[2][q] * hs * (c15 * x * y);
        me[5] = wacc[2][q] * hs * (c15 * y * z);
        me[6] = wacc[2][q] * hs * (0.5f * c5 * (3.f * z * z - 1.f));
        me[7] = wacc[2][q] * hs * (c15 * x * z);
        me[8] = wacc[2][q] * hs * (0.5f * c15 * (x * x - y * y));
    }
}

// ---------------------------------------------------------------------------
// Layers 1/2: r9/r10-proven pk-fp32 tp_edge, SINGLE-pass w2t staging.
// (r11/r12's two-pass variant put __syncthreads inside the acc live range ->
// compiler demoted acc/hf to scratch -> 6+ GB spill traffic. Do NOT put
// barriers inside the accumulator live range.)
// LDS: w2t fp32 [120][68] (emb aliased) + hid bf16 [128][72] = 51072 B
// -> 3 blocks/CU, VGPR 80, zero scratch (r9/r10 measured 240-265 us).
// ---------------------------------------------------------------------------
__launch_bounds__(256, 3)
__global__ void tp_edge(const float* __restrict__ evp, const int* __restrict__ srcs,
                        const float* __restrict__ h,
                        const float* __restrict__ w1, const float* __restrict__ b1,
                        const float* __restrict__ w2, const float* __restrict__ b2,
                        float* __restrict__ mbuf)
{
    __shared__ float w2t[120 * 68];
    __shared__ unsigned short hid_s[128 * 72];
    float* emb_s = w2t;

    const int tid = threadIdx.x;
    const int e0 = blockIdx.x * 128;

    for (int idx = tid; idx < 2048; idx += 256) {
        int e = idx >> 4, i = idx & 15;
        const float* ep = evp + (size_t)(e0 + e) * 3;
        float ex = ep[0], ey = ep[1], ez = ep[2];
        float r = sqrtf(ex * ex + ey * ey + ez * ez + 1e-12f);
        float d = r * (17.0f / 3.0f) - (float)(i + 1);
        float f = 0.0f;
        if (fabsf(d) < 1.0f) f = 8.433572869f * __expf(-2.0f / (1.0f - d * d));
        emb_s[e * 17 + i] = f;
    }
    __syncthreads();

    {
        const int egp = tid >> 3;
        const int jb = (tid & 7) * 8;
        f32x2v acc2[2][8];
        #pragma unroll
        for (int pr = 0; pr < 2; ++pr)
            #pragma unroll
            for (int k = 0; k < 8; ++k) { float bb = b1[jb + k]; acc2[pr][k] = mk2(bb, bb); }
        #pragma unroll
        for (int i = 0; i < 16; ++i) {
            float4 wa = *(const float4*)&w1[i * 64 + jb];
            float4 wb = *(const float4*)&w1[i * 64 + jb + 4];
            #pragma unroll
            for (int pr = 0; pr < 2; ++pr) {
                f32x2v evv = mk2(emb_s[(egp * 4 + 2 * pr) * 17 + i],
                                 emb_s[(egp * 4 + 2 * pr + 1) * 17 + i]);
                acc2[pr][0] += evv * wa.x; acc2[pr][1] += evv * wa.y;
                acc2[pr][2] += evv * wa.z; acc2[pr][3] += evv * wa.w;
                acc2[pr][4] += evv * wb.x; acc2[pr][5] += evv * wb.y;
                acc2[pr][6] += evv * wb.z; acc2[pr][7] += evv * wb.w;
            }
        }
        #pragma unroll
        for (int pr = 0; pr < 2; ++pr) {
            #pragma unroll
            for (int u = 0; u < 2; ++u) {
                unsigned int us[8];
                #pragma unroll
                for (int k = 0; k < 8; ++k) {
                    unsigned int b = __float_as_uint(silu_f(acc2[pr][k][u]));
                    b += 0x7fffu + ((b >> 16) & 1u);
                    us[k] = b >> 16;
                }
                uint4 pk;
                pk.x = us[0] | (us[1] << 16);
                pk.y = us[2] | (us[3] << 16);
                pk.z = us[4] | (us[5] << 16);
                pk.w = us[6] | (us[7] << 16);
                *(uint4*)&hid_s[(egp * 4 + 2 * pr + u) * 72 + jb] = pk;
            }
        }
    }
    __syncthreads();

    for (int idx = tid; idx < 64 * 120; idx += 256) {
        int j = idx / 120, o = idx - j * 120;
        w2t[o * 68 + j] = w2[idx];
    }
    __syncthreads();

    const int c = tid & 7, g = (tid >> 3) & 7, wv_ = tid >> 6;
    f32x2v acc[15][2];
    #pragma unroll
    for (int p = 0; p < 15; ++p) {
        float bb = b2[p * 8 + c];
        acc[p][0] = mk2(bb, bb);
        acc[p][1] = mk2(bb, bb);
    }

    for (int jb = 0; jb < 64; jb += 8) {
        f32x2v hf[8][2];
        #pragma unroll
        for (int pr = 0; pr < 2; ++pr) {
            uint4 h0 = *(const uint4*)&hid_s[(wv_ * 32 + (2 * pr) * 8 + g) * 72 + jb];
            uint4 h1 = *(const uint4*)&hid_s[(wv_ * 32 + (2 * pr + 1) * 8 + g) * 72 + jb];
            hf[0][pr] = mk2(__uint_as_float(h0.x << 16),        __uint_as_float(h1.x << 16));
            hf[1][pr] = mk2(__uint_as_float(h0.x & 0xffff0000u), __uint_as_float(h1.x & 0xffff0000u));
            hf[2][pr] = mk2(__uint_as_float(h0.y << 16),        __uint_as_float(h1.y << 16));
            hf[3][pr] = mk2(__uint_as_float(h0.y & 0xffff0000u), __uint_as_float(h1.y & 0xffff0000u));
            hf[4][pr] = mk2(__uint_as_float(h0.z << 16),        __uint_as_float(h1.z << 16));
            hf[5][pr] = mk2(__uint_as_float(h0.z & 0xffff0000u), __uint_as_float(h1.z & 0xffff0000u));
            hf[6][pr] = mk2(__uint_as_float(h0.w << 16),        __uint_as_float(h1.w << 16));
            hf[7][pr] = mk2(__uint_as_float(h0.w & 0xffff0000u), __uint_as_float(h1.w & 0xffff0000u));
        }
        #pragma unroll
        for (int p = 0; p < 15; ++p) {
            float4 wa = *(const float4*)&w2t[(p * 8 + c) * 68 + jb];
            float4 wb = *(const float4*)&w2t[(p * 8 + c) * 68 + jb + 4];
            #pragma unroll
            for (int pr = 0; pr < 2; ++pr) {
                acc[p][pr] += hf[0][pr] * wa.x + hf[1][pr] * wa.y + hf[2][pr] * wa.z + hf[3][pr] * wa.w
                            + hf[4][pr] * wb.x + hf[5][pr] * wb.y + hf[6][pr] * wb.z + hf[7][pr] * wb.w;
            }
        }
    }

    const int ebase = wv_ * 32 + g;
    int sn[4];
    #pragma unroll
    for (int q = 0; q < 4; ++q) sn[q] = srcs[e0 + ebase + 8 * q];

    #pragma unroll
    for (int hh = 0; hh < 2; ++hh) {
        const float* hn0 = h + (size_t)sn[2 * hh] * 72 + c * 9;
        const float* hn1 = h + (size_t)sn[2 * hh + 1] * 72 + c * 9;
        const float* me0 = mbuf + (size_t)(e0 + ebase + 8 * (2 * hh)) * 72 + c * 9;
        const float* me1 = mbuf + (size_t)(e0 + ebase + 8 * (2 * hh + 1)) * 72 + c * 9;

        f32x2v as = mk2(hn0[0], hn1[0]);
        f32x2v av[3], at[5], bv[3], bt[5];
        #pragma unroll
        for (int i = 0; i < 3; ++i) av[i] = mk2(hn0[1 + i], hn1[1 + i]);
        #pragma unroll
        for (int i = 0; i < 5; ++i) at[i] = mk2(hn0[4 + i], hn1[4 + i]);
        f32x2v bs = mk2(silu_f(me0[0]), silu_f(me1[0]));
        #pragma unroll
        for (int i = 0; i < 3; ++i) bv[i] = mk2(me0[1 + i], me1[1 + i]);
        #pragma unroll
        for (int i = 0; i < 5; ++i) bt[i] = mk2(me0[4 + i], me1[4 + i]);

        f32x2v wvv[15];
        #pragma unroll
        for (int p = 0; p < 15; ++p) wvv[p] = acc[p][hh];

        f32x2v ms, mv[3], mt[5];
        tp_uuu2(wvv, as, av, at, bs, bv, bt, ms, mv, mt);

        float* mo0 = mbuf + (size_t)(e0 + ebase + 8 * (2 * hh)) * 72 + c * 9;
        float* mo1 = mbuf + (size_t)(e0 + ebase + 8 * (2 * hh + 1)) * 72 + c * 9;
        mo0[0] = ms[0]; mo1[0] = ms[1];
        #pragma unroll
        for (int i = 0; i < 3; ++i) { mo0[1 + i] = mv[i][0]; mo1[1 + i] = mv[i][1]; }
        #pragma unroll
        for (int i = 0; i < 5; ++i) { mo0[4 + i] = mt[i][0]; mo1[4 + i] = mt[i][1]; }
    }
}

// ---------------------------------------------------------------------------
// Node updates: sequential CSR-span gather of slot-ordered mbuf
// ---------------------------------------------------------------------------
__global__ void node0(const int* __restrict__ xs, const float* __restrict__ embw,
                      const float* __restrict__ lin0, const float* __restrict__ mbuf,
                      const int* __restrict__ off, float* __restrict__ h)
{
    int idx = blockIdx.x * 256 + threadIdx.x;
    int n = idx >> 3, c = idx & 7;
    int xb = xs[n] * 8;
    float dot = 0.f;
    #pragma unroll
    for (int d = 0; d < 8; ++d) dot += embw[xb + d] * lin0[d * 8 + c];

    float an[9];
    #pragma unroll
    for (int i = 0; i < 9; ++i) an[i] = 0.f;
    const int beg = off[n], end = off[n + 1];
    for (int p = beg; p < end; ++p) {
        const float* me = mbuf + (size_t)p * 72 + c * 9;
        #pragma unroll
        for (int i = 0; i < 9; ++i) an[i] += me[i];
    }

    float* hn = h + (size_t)n * 72 + c * 9;
    hn[0] = silu_f(an[0] * 0.25f + dot * 0.35355339f);
    #pragma unroll
    for (int i = 1; i < 9; ++i) hn[i] = an[i] * 0.25f;
}

__global__ void node12(const float* __restrict__ hin, const float* __restrict__ lin,
                       const float* __restrict__ mbuf, const int* __restrict__ off,
                       float* __restrict__ hout)
{
    int idx = blockIdx.x * 256 + threadIdx.x;
    int n = idx >> 3, d = idx & 7;

    float an[9];
    #pragma unroll
    for (int i = 0; i < 9; ++i) an[i] = 0.f;
    const int beg = off[n], end = off[n + 1];
    for (int p = beg; p < end; ++p) {
        const float* me = mbuf + (size_t)p * 72 + d * 9;
        #pragma unroll
        for (int i = 0; i < 9; ++i) an[i] += me[i];
    }

    const float* hn = hin + (size_t)n * 72;
    float* ho = hout + (size_t)n * 72 + d * 9;

    float s = 0.f;
    #pragma unroll
    for (int c = 0; c < 8; ++c) s += hn[c * 9] * lin[c * 8 + d];
    ho[0] = silu_f(s * 0.35355339f + an[0] * 0.25f);
    #pragma unroll
    for (int i = 0; i < 3; ++i) {
        float v = 0.f;
        #pragma unroll
        for (int c = 0; c < 8; ++c) v += hn[c * 9 + 1 + i] * lin[64 + c * 8 + d];
        ho[1 + i] = v * 0.35355339f + an[1 + i] * 0.25f;
    }
    #pragma unroll
    for (int i = 0; i < 5; ++i) {
        float t = 0.f;
        #pragma unroll
        for (int c = 0; c < 8; ++c) t += hn[c * 9 + 4 + i] * lin[128 + c * 8 + d];
        ho[4 + i] = t * 0.35355339f + an[4 + i] * 0.25f;
    }
}

// Fused final node update + output head: h record staged in LDS, never HBM
__global__ void node12_out(const float* __restrict__ hin, const float* __restrict__ lin,
                           const float* __restrict__ mbuf, const int* __restrict__ off,
                           const float* __restrict__ outw, float* __restrict__ out)
{
    __shared__ float hrec[32][72];
    int idx = blockIdx.x * 256 + threadIdx.x;
    int n = idx >> 3, d = idx & 7;
    int nl = threadIdx.x >> 3;

    float an[9];
    #pragma unroll
    for (int i = 0; i < 9; ++i) an[i] = 0.f;
    const int beg = off[n], end = off[n + 1];
    for (int p = beg; p < end; ++p) {
        const float* me = mbuf + (size_t)p * 72 + d * 9;
        #pragma unroll
        for (int i = 0; i < 9; ++i) an[i] += me[i];
    }

    const float* hn = hin + (size_t)n * 72;
    float* ho = &hrec[nl][d * 9];

    float s = 0.f;
    #pragma unroll
    for (int c = 0; c < 8; ++c) s += hn[c * 9] * lin[c * 8 + d];
    ho[0] = silu_f(s * 0.35355339f + an[0] * 0.25f);
    #pragma unroll
    for (int i = 0; i < 3; ++i) {
        float v = 0.f;
        #pragma unroll
        for (int c = 0; c < 8; ++c) v += hn[c * 9 + 1 + i] * lin[64 + c * 8 + d];
        ho[1 + i] = v * 0.35355339f + an[1 + i] * 0.25f;
    }
    #pragma unroll
    for (int i = 0; i < 5; ++i) {
        float t = 0.f;
        #pragma unroll
        for (int c = 0; c < 8; ++c) t += hn[c * 9 + 4 + i] * lin[128 + c * 8 + d];
        ho[4 + i] = t * 0.35355339f + an[4 + i] * 0.25f;
    }
    __syncthreads();

    const float* hr = &hrec[nl][0];
    float sv[8], vv[24], tv[40];
    #pragma unroll
    for (int i = 0; i < 8; ++i) {
        sv[i] = hr[i * 9];
        #pragma unroll
        for (int q = 0; q < 3; ++q) vv[i * 3 + q] = hr[i * 9 + 1 + q];
        #pragma unroll
        for (int q = 0; q < 5; ++q) tv[i * 5 + q] = hr[i * 9 + 4 + q];
    }
    float acc = 0.f;
    #pragma unroll
    for (int i = 0; i < 8; ++i) {
        #pragma unroll
        for (int j = 0; j < 8; ++j) {
            float dv = vv[i*3+0]*vv[j*3+0] + vv[i*3+1]*vv[j*3+1] + vv[i*3+2]*vv[j*3+2];
            float dt = tv[i*5+0]*tv[j*5+0] + tv[i*5+1]*tv[j*5+1] + tv[i*5+2]*tv[j*5+2]
                     + tv[i*5+3]*tv[j*5+3] + tv[i*5+4]*tv[j*5+4];
            int o = (i * 8 + j) * 8 + d;
            acc += sv[i] * sv[j] * outw[o]
                 + dv * 0.57735027f * outw[512 + o]
                 + dt * 0.44721360f * outw[1024 + o];
        }
    }
    out[n * 8 + d] = acc * 0.072168784f;
}

// ---------------------------------------------------------------------------
extern "C" void kernel_launch(void* const* d_in, const int* in_sizes, int n_in,
                              void* d_out, int out_size, void* d_ws, size_t ws_size,
                              hipStream_t stream)
{
    const int*   x    = (const int*)  d_in[0];
    const int*   eidx = (const int*)  d_in[1];
    const float* ev   = (const float*)d_in[2];
    const float* embw = (const float*)d_in[3];
    const float* lin0 = (const float*)d_in[4];
    const float* lin1 = (const float*)d_in[5];
    const float* lin2 = (const float*)d_in[6];
    const float* outw = (const float*)d_in[7];
    const float* r0w1 = (const float*)d_in[8];
    const float* r0b1 = (const float*)d_in[9];
    const float* r0w2 = (const float*)d_in[10];
    const float* r0b2 = (const float*)d_in[11];
    const float* r1w1 = (const float*)d_in[12];
    const float* r1b1 = (const float*)d_in[13];
    const float* r1w2 = (const float*)d_in[14];
    const float* r1b2 = (const float*)d_in[15];
    const float* r2w1 = (const float*)d_in[16];
    const float* r2b1 = (const float*)d_in[17];
    const float* r2w2 = (const float*)d_in[18];
    const float* r2b2 = (const float*)d_in[19];

    float* mbuf = (float*)d_ws;                          // EDGES*72 f32
    float* hA   = mbuf + (size_t)EDGES * 72;             // NODES*72
    float* hB   = hA + (size_t)NODES * 72;               // NODES*72
    float* evp  = hB + (size_t)NODES * 72;               // EDGES*3
    int*   deg    = (int*)(evp + (size_t)EDGES * 3);     // NODES
    int*   off    = deg + NODES;                         // NODES+1
    int*   cursor = off + NODES + 1;                     // NODES
    int*   srcs   = cursor + NODES;                      // EDGES

    const int EBI = (EDGES + 255) / 256;
    const int EB  = EDGES / 128;
    const int NBK = NODES * 8 / 256;

    // CSR build + fused permutation
    hipMemsetAsync(deg, 0, NODES * sizeof(int), stream);
    deg_kernel<<<EBI, 256, 0, stream>>>(eidx, deg);
    scan_kernel<<<1, 1024, 0, stream>>>(deg, off, cursor);
    build_kernel<<<EBI, 256, 0, stream>>>(eidx, ev, cursor, evp, srcs);

    // Layer 0
    layer0_edge<<<EB, 256, 0, stream>>>(evp, srcs, x, embw, r0w1, r0b1, r0w2, r0b2, mbuf);
    node0<<<NBK, 256, 0, stream>>>(x, embw, lin0, mbuf, off, hA);

    // Layer 1
    tp_edge<<<EB, 256, 0, stream>>>(evp, srcs, hA, r1w1, r1b1, r1w2, r1b2, mbuf);
    node12<<<NBK, 256, 0, stream>>>(hA, lin1, mbuf, off, hB);

    // Layer 2 + output head (fused)
    tp_edge<<<EB, 256, 0, stream>>>(evp, srcs, hB, r2w1, r2b1, r2w2, r2b2, mbuf);
    node12_out<<<NBK, 256, 0, stream>>>(hB, lin2, mbuf, off, outw, (float*)d_out);
}